// Round 7
// baseline (469.573 us; speedup 1.0000x reference)
//
#include <hip/hip_runtime.h>
#include <stdint.h>
#include <stddef.h>

typedef __bf16 bf16;
typedef __bf16 bf16x4 __attribute__((ext_vector_type(4)));
typedef __bf16 bf16x8 __attribute__((ext_vector_type(8)));
typedef float f32x4 __attribute__((ext_vector_type(4)));
typedef unsigned long long u64;

#define BATCH 4
#define G_LEN 1024
#define S_LEN 4096
#define DM 512
#define NH 8
#define DK 64
#define CIS_WORDS (G_LEN * (S_LEN / 64))   // 65536
#define PSTR 72                            // P row stride in bf16 (144B: 8B/16B aligned)

__device__ __forceinline__ f32x4 mfma16(bf16x8 a, bf16x8 b, f32x4 c) {
    return __builtin_amdgcn_mfma_f32_16x16x32_bf16(a, b, c, 0, 0, 0);
}

// ---------------------------------------------------------------------------
// cis dtype detection (bool vs int32) — see round 1 notes. flag=1 -> bytes.
// ---------------------------------------------------------------------------
__global__ void detect_cis(const unsigned char* __restrict__ cis, int* __restrict__ flag) {
    int any = 0;
    for (int i = threadIdx.x; i < 16384; i += 64)
        any |= cis[4 * i + 1];
    #pragma unroll
    for (int off = 1; off < 64; off <<= 1) any |= __shfl_xor(any, off);
    if (threadIdx.x == 0) flag[0] = (any != 0) ? 1 : 0;
}

// ---------------------------------------------------------------------------
// Pack cis[g][s] and mask[b][s] into bit-words (one wave per u64 via ballot).
// ---------------------------------------------------------------------------
__global__ __launch_bounds__(256) void pack_masks(
    const void* __restrict__ cisv, const int* __restrict__ mask,
    const int* __restrict__ flag, u64* __restrict__ cbits, u64* __restrict__ mbits)
{
    const int wid  = blockIdx.x * 4 + (threadIdx.x >> 6);
    const int lane = threadIdx.x & 63;
    if (wid < CIS_WORDS) {
        int v;
        if (flag[0]) v = ((const unsigned char*)cisv)[(size_t)wid * 64 + lane];
        else         v = ((const int*)cisv)[(size_t)wid * 64 + lane];
        const u64 bits = __ballot(v != 0);
        if (lane == 0) cbits[wid] = bits;
    } else if (wid < CIS_WORDS + BATCH * (S_LEN / 64)) {
        const int w2 = wid - CIS_WORDS;               // b*64 + sw
        const u64 bits = __ballot(mask[w2 * 64 + lane] != 0);
        if (lane == 0) mbits[w2] = bits;
    }
}

// ---------------------------------------------------------------------------
// GEMM: Y[m][n] = (sum_k X[m][k]*W[n][k] + bias[n] (+ shift)) * oscale
// ---------------------------------------------------------------------------
template<int A_IS_BF16, int TRANS_OUT, int OUT_F32, int ROWS_PER_B>
__global__ __launch_bounds__(256) void gemm_proj(
    const void* __restrict__ Ap, const float* __restrict__ W,
    const float* __restrict__ bias, const float* __restrict__ shift,
    void* __restrict__ Out, float oscale)
{
    __shared__ bf16 As[64][72];
    __shared__ bf16 Bs[64][72];
    const int tid  = threadIdx.x;
    const int lane = tid & 63;
    const int wave = tid >> 6;
    const int l15  = lane & 15;
    const int l4   = lane >> 4;
    const int m0   = blockIdx.x * 64;
    const int n0   = blockIdx.y * 64;

    f32x4 acc[4] = {};

    for (int kt = 0; kt < DM; kt += 64) {
        #pragma unroll
        for (int i = 0; i < 4; ++i) {
            const int q   = tid + i * 256;
            const int row = q >> 4;
            const int kq  = (q & 15) * 4;
            bf16x4 av;
            if (A_IS_BF16) {
                av = *(const bf16x4*)((const bf16*)Ap + (size_t)(m0 + row) * DM + kt + kq);
            } else {
                const float4 v = *(const float4*)((const float*)Ap + (size_t)(m0 + row) * DM + kt + kq);
                av[0] = (bf16)v.x; av[1] = (bf16)v.y; av[2] = (bf16)v.z; av[3] = (bf16)v.w;
            }
            *(bf16x4*)&As[row][kq] = av;
            const float4 w = *(const float4*)(W + (size_t)(n0 + row) * DM + kt + kq);
            bf16x4 bv;
            bv[0] = (bf16)w.x; bv[1] = (bf16)w.y; bv[2] = (bf16)w.z; bv[3] = (bf16)w.w;
            *(bf16x4*)&Bs[row][kq] = bv;
        }
        __syncthreads();
        #pragma unroll
        for (int ks = 0; ks < 64; ks += 32) {
            const bf16x8 a = *(const bf16x8*)&As[wave * 16 + l15][ks + 8 * l4];
            #pragma unroll
            for (int n = 0; n < 4; ++n) {
                const bf16x8 b = *(const bf16x8*)&Bs[n * 16 + l15][ks + 8 * l4];
                acc[n] = mfma16(a, b, acc[n]);
            }
        }
        __syncthreads();
    }

    #pragma unroll
    for (int n = 0; n < 4; ++n) {
        const int col = n0 + n * 16 + l15;
        const float bv = bias[col];
        #pragma unroll
        for (int r = 0; r < 4; ++r) {
            const int m = m0 + wave * 16 + l4 * 4 + r;
            float v = acc[n][r] + bv;
            if (shift) v += shift[(m / ROWS_PER_B) * DM + col];
            v *= oscale;
            if (TRANS_OUT) {
                ((bf16*)Out)[((size_t)(m / ROWS_PER_B) * DM + col) * ROWS_PER_B + (m % ROWS_PER_B)] = (bf16)v;
            } else if (OUT_F32) {
                ((float*)Out)[(size_t)m * DM + col] = v;
            } else {
                ((bf16*)Out)[(size_t)m * DM + col] = (bf16)v;
            }
        }
    }
}

// ---------------------------------------------------------------------------
// Flash attention, swapped-QK^T / lane-local softmax.
// Grid 2048 blocks x 4 waves; waves share 16 q-rows, split S in 4 chunks.
// scores = mfma(K,Q): lane holds 16 scores of q-row l15 (s = sub*16+l4*4+r).
// Softmax: NO max-subtraction (scores bounded, f32-safe), no hot-loop shfl.
// launch_bounds(256,8): kernel fits 64-VGPR budget (52 used at (256,4)) ->
// double the wave pool; round 6 showed all pipes idle = latency-bound.
// Spill tripwire: WRITE_SIZE must stay ~4MB (round 3 blew up to 865MB).
// ---------------------------------------------------------------------------
__global__ __launch_bounds__(256, 8) void attn_kernel(
    const bf16* __restrict__ Qb, const bf16* __restrict__ Kb,
    const bf16* __restrict__ Vt, const u64* __restrict__ mbits,
    const u64* __restrict__ cbits, bf16* __restrict__ AO)
{
    __shared__ __align__(16) char smem_raw[17408];
    bf16*  Pw = (bf16*)smem_raw;   // [4 waves][16 rows][PSTR]
    float* MB = (float*)smem_raw;  // L[4][4][16] (256 f) | ACC[4][16][64]

    const int tid  = threadIdx.x;
    const int lane = tid & 63;
    const int wave = tid >> 6;
    const int l15  = lane & 15;
    const int l4   = lane >> 4;

    // XCD-aware remap (bijective: 2048 = 8 XCD * 4 pairs * 64 g-tiles)
    const int flat = blockIdx.x + 64 * (blockIdx.y + 8 * blockIdx.z);
    const int xcd  = flat & 7;
    const int slot = flat >> 3;
    const int pr   = xcd * 4 + (slot >> 6);   // (b,h) pair 0..31
    const int b    = pr >> 3;
    const int h    = pr & 7;
    const int g0   = (slot & 63) * 16;

    const bf16* qrow = Qb + (size_t)(b * G_LEN + g0 + l15) * DM + h * DK + 8 * l4;
    const bf16x8 q0 = *(const bf16x8*)qrow;
    const bf16x8 q1 = *(const bf16x8*)(qrow + 32);

    const bf16* Kbase = Kb + (size_t)b * S_LEN * DM + h * DK;
    const bf16* Vbase = Vt + (size_t)(b * NH + h) * DK * S_LEN;
    const u64*  mb = mbits + b * (S_LEN / 64);
    const u64*  cb = cbits + (size_t)(g0 + l15) * (S_LEN / 64);  // this lane's q-row

    f32x4 acc[4] = {};
    float lsum = 0.f;

    bf16* Pme = Pw + (wave * 16 + l15) * PSTR;   // write base (row q=l15)

    const int sbeg = wave * (S_LEN / 4);
    for (int s0 = sbeg; s0 < sbeg + (S_LEN / 4); s0 += 64) {
        const int sw = s0 >> 6;
        // ---- scores (swapped): c[sub] = D[s-pos][q]; lane: q=l15, s=sub*16+l4*4+r
        f32x4 c[4];
        #pragma unroll
        for (int sub = 0; sub < 4; ++sub) {
            const bf16* krow = Kbase + (size_t)(s0 + sub * 16 + l15) * DM + 8 * l4;
            const bf16x8 k0 = *(const bf16x8*)krow;
            const bf16x8 k1 = *(const bf16x8*)(krow + 32);
            f32x4 t = {0.f, 0.f, 0.f, 0.f};
            t = mfma16(k0, q0, t);
            t = mfma16(k1, q1, t);
            c[sub] = t;
        }

        // ---- one mask word for this lane's q-row; bit s = sub*16 + l4*4 + r
        const u64 kw = (cb[sw] & mb[sw]) >> (l4 * 4);
        const uint32_t kwlo = (uint32_t)kw, kwhi = (uint32_t)(kw >> 32);

        // ---- p = keep ? exp(score) : 0   (no max-sub; no cross-lane ops)
        float p[4][4];
        #pragma unroll
        for (int sub = 0; sub < 4; ++sub) {
            const uint32_t w = (sub < 2) ? kwlo : kwhi;
            #pragma unroll
            for (int r = 0; r < 4; ++r) {
                const float e = __expf(c[sub][r]);
                p[sub][r] = ((w >> ((sub & 1) * 16 + r)) & 1u) ? e : 0.f;
            }
        }
        // row-sum tree (per-lane partial of q-row l15)
        float s_a = (p[0][0] + p[0][1]) + (p[0][2] + p[0][3]);
        float s_b = (p[1][0] + p[1][1]) + (p[1][2] + p[1][3]);
        float s_c = (p[2][0] + p[2][1]) + (p[2][2] + p[2][3]);
        float s_d = (p[3][0] + p[3][1]) + (p[3][2] + p[3][3]);
        lsum += (s_a + s_b) + (s_c + s_d);

        // ---- P -> LDS: 4 x ds_write_b64, row q=l15, k = sub*16 + l4*4 .. +3
        #pragma unroll
        for (int sub = 0; sub < 4; ++sub) {
            bf16x4 v;
            v[0] = (bf16)p[sub][0]; v[1] = (bf16)p[sub][1];
            v[2] = (bf16)p[sub][2]; v[3] = (bf16)p[sub][3];
            *(bf16x4*)(Pme + sub * 16 + l4 * 4) = v;
        }
        // same-wave LDS ops complete in order; compiler inserts lgkmcnt for the
        // read->MFMA register hazard. No barrier, no sched fence -> next-tile
        // K loads are free to hoist above this point.

        // ---- PV: A-frag = P[q=l15][8*l4+j], B-frag = Vt[d][s]
        const bf16* Pr = Pw + (wave * 16 + l15) * PSTR;
        const bf16x8 pa0 = *(const bf16x8*)(Pr + 8 * l4);
        const bf16x8 pa1 = *(const bf16x8*)(Pr + 32 + 8 * l4);
        #pragma unroll
        for (int n = 0; n < 4; ++n) {
            const bf16* vrow = Vbase + (size_t)(n * 16 + l15) * S_LEN + s0 + 8 * l4;
            const bf16x8 v0 = *(const bf16x8*)vrow;
            const bf16x8 v1 = *(const bf16x8*)(vrow + 32);
            acc[n] = mfma16(pa0, v0, acc[n]);
            acc[n] = mfma16(pa1, v1, acc[n]);
        }
    }

    // ---- merge partials in LDS (no max bookkeeping: plain sums) ----
    __syncthreads();   // all waves done with P region
    MB[wave * 64 + l4 * 16 + l15] = lsum;                  // L[wave][l4][row]
    #pragma unroll
    for (int r = 0; r < 4; ++r)
        #pragma unroll
        for (int n = 0; n < 4; ++n)
            MB[256 + (wave * 16 + l4 * 4 + r) * 64 + n * 16 + l15] = acc[n][r];
    __syncthreads();

    #pragma unroll
    for (int i = 0; i < 4; ++i) {
        const int idx = tid + i * 256;
        const int row = idx >> 6;
        const int d   = idx & 63;
        float wl = 0.f, o = 0.f;
        #pragma unroll
        for (int c2 = 0; c2 < 4; ++c2) {
            wl += MB[c2 * 64 + 0 * 16 + row] + MB[c2 * 64 + 1 * 16 + row]
                + MB[c2 * 64 + 2 * 16 + row] + MB[c2 * 64 + 3 * 16 + row];
            o  += MB[256 + (c2 * 16 + row) * 64 + d];
        }
        const float inv = wl > 0.f ? 1.f / wl : 0.f;
        AO[(size_t)(b * G_LEN + g0 + row) * DM + h * DK + d] = (bf16)(o * inv);
    }
}

// ---------------------------------------------------------------------------
// Row LayerNorm: one block per row (512 cols), 256 threads.
// ---------------------------------------------------------------------------
__global__ __launch_bounds__(256) void out_ln(
    const float* __restrict__ Y, const float* __restrict__ gam,
    const float* __restrict__ bet, float* __restrict__ out)
{
    const int row = blockIdx.x;
    const int tid = threadIdx.x;
    const float x0 = Y[(size_t)row * DM + tid];
    const float x1 = Y[(size_t)row * DM + 256 + tid];
    float s  = x0 + x1;
    float sq = x0 * x0 + x1 * x1;
    #pragma unroll
    for (int off = 1; off < 64; off <<= 1) {
        s  += __shfl_xor(s, off);
        sq += __shfl_xor(sq, off);
    }
    __shared__ float ss[4], ssq[4];
    const int wave = tid >> 6;
    if ((tid & 63) == 0) { ss[wave] = s; ssq[wave] = sq; }
    __syncthreads();
    s  = ss[0] + ss[1] + ss[2] + ss[3];
    sq = ssq[0] + ssq[1] + ssq[2] + ssq[3];
    const float mu  = s * (1.f / 512.f);
    const float var = sq * (1.f / 512.f) - mu * mu;
    const float rs  = rsqrtf(var + 1e-5f);
    out[(size_t)row * DM + tid]       = (x0 - mu) * rs * gam[tid] + bet[tid];
    out[(size_t)row * DM + 256 + tid] = (x1 - mu) * rs * gam[tid + 256] + bet[tid + 256];
}

// ---------------------------------------------------------------------------
extern "C" void kernel_launch(void* const* d_in, const int* in_sizes, int n_in,
                              void* d_out, int out_size, void* d_ws, size_t ws_size,
                              hipStream_t stream) {
    const float* queries     = (const float*)d_in[0];   // [4,1024,512]
    const float* keys_values = (const float*)d_in[1];   // [4,4096,512]
    const float* dq          = (const float*)d_in[2];   // [4,1,512]
    const float* dk          = (const float*)d_in[3];   // [4,1,512]
    const int*   mask        = (const int*)d_in[4];     // [4,4096]
    const void*  cis         = d_in[5];                 // [1024,4096] bool (dtype detected)
    const float* wq_w = (const float*)d_in[6];
    const float* wq_b = (const float*)d_in[7];
    const float* wk_w = (const float*)d_in[8];
    const float* wk_b = (const float*)d_in[9];
    const float* wv_w = (const float*)d_in[10];
    const float* wv_b = (const float*)d_in[11];
    const float* wo_w = (const float*)d_in[12];
    const float* wo_b = (const float*)d_in[13];
    const float* ln_g = (const float*)d_in[14];
    const float* ln_b = (const float*)d_in[15];
    float* out = (float*)d_out;

    char* ws = (char*)d_ws;
    bf16*  Qbf = (bf16*)(ws);                                   //  4 MB [4096,512] (pre-scaled x0.125)
    bf16*  Kbf = (bf16*)(ws + (4u << 20));                      // 16 MB [16384,512]
    bf16*  Vt  = (bf16*)(ws + (20u << 20));                     // 16 MB [4,8,64,4096]
    bf16*  AO  = (bf16*)(ws + (36u << 20));                     //  4 MB [4096,512]
    float* Yw  = (float*)(ws + (40u << 20));                    //  8 MB [4096,512]
    int*   cisflag = (int*)(ws + (48u << 20));                  //  4 B
    u64*   mbits   = (u64*)(ws + (48u << 20) + 4096);           //  2 KB [4][64]
    u64*   cbits   = (u64*)(ws + (48u << 20) + 8192);           // 512 KB [1024][64]

    detect_cis<<<1, 64, 0, stream>>>((const unsigned char*)cis, cisflag);
    pack_masks<<<(CIS_WORDS + BATCH * (S_LEN / 64) + 3) / 4, 256, 0, stream>>>(
        cis, mask, cisflag, cbits, mbits);

    // Projections. Q pre-scaled by 1/sqrt(d_k)=0.125 (exact pow2, folded here).
    gemm_proj<0, 0, 0, 1024><<<dim3(64, 8),  256, 0, stream>>>(queries,     wq_w, wq_b, dq,      Qbf, 0.125f);
    gemm_proj<0, 0, 0, 4096><<<dim3(256, 8), 256, 0, stream>>>(keys_values, wk_w, wk_b, dk,      Kbf, 1.0f);
    gemm_proj<0, 1, 0, 4096><<<dim3(256, 8), 256, 0, stream>>>(keys_values, wv_w, wv_b, nullptr, Vt,  1.0f);

    // Fused masked flash attention (swapped-QK, lane-local softmax, 8 w/EU)
    attn_kernel<<<dim3(64, 8, 4), 256, 0, stream>>>(Qbf, Kbf, Vt, mbits, cbits, AO);

    // Output projection (bf16 A) -> f32 scratch
    gemm_proj<1, 0, 1, 1024><<<dim3(64, 8),  256, 0, stream>>>(AO, wo_w, wo_b, nullptr, Yw, 1.0f);

    // LayerNorm -> d_out
    out_ln<<<4096, 256, 0, stream>>>(Yw, ln_g, ln_b, out);
}

// Round 8
// 311.677 us; speedup vs baseline: 1.5066x; 1.5066x over previous
//
#include <hip/hip_runtime.h>
#include <stdint.h>
#include <stddef.h>

typedef __bf16 bf16;
typedef __bf16 bf16x4 __attribute__((ext_vector_type(4)));
typedef __bf16 bf16x8 __attribute__((ext_vector_type(8)));
typedef float f32x4 __attribute__((ext_vector_type(4)));
typedef float f32x16 __attribute__((ext_vector_type(16)));
typedef unsigned long long u64;

#define BATCH 4
#define G_LEN 1024
#define S_LEN 4096
#define DM 512
#define NH 8
#define DK 64
#define CIS_WORDS (G_LEN * (S_LEN / 64))   // 65536

__device__ __forceinline__ f32x4 mfma16(bf16x8 a, bf16x8 b, f32x4 c) {
    return __builtin_amdgcn_mfma_f32_16x16x32_bf16(a, b, c, 0, 0, 0);
}
__device__ __forceinline__ f32x16 mfma32(bf16x8 a, bf16x8 b, f32x16 c) {
    return __builtin_amdgcn_mfma_f32_32x32x16_bf16(a, b, c, 0, 0, 0);
}
// v_cvt_pk_bf16_f32: dst.lo = bf16(lo), dst.hi = bf16(hi). No builtin (m240).
__device__ __forceinline__ uint32_t cvtpk(float lo, float hi_) {
    uint32_t r;
    asm("v_cvt_pk_bf16_f32 %0, %1, %2" : "=v"(r) : "v"(lo), "v"(hi_));
    return r;
}
// v_permlane32_swap_b32: a.lanes[32:64] <-> b.lanes[0:32] (gfx950).
__device__ __forceinline__ void pswap(uint32_t& a, uint32_t& b) {
    asm("v_permlane32_swap_b32 %0, %1" : "+v"(a), "+v"(b));
}
__device__ __forceinline__ bf16x8 mk8(uint32_t a, uint32_t b, uint32_t c, uint32_t d) {
    union { uint32_t u[4]; bf16x8 v; } x;
    x.u[0] = a; x.u[1] = b; x.u[2] = c; x.u[3] = d;
    return x.v;
}

// ---------------------------------------------------------------------------
// cis dtype detection (bool vs int32) — see round 1 notes. flag=1 -> bytes.
// ---------------------------------------------------------------------------
__global__ void detect_cis(const unsigned char* __restrict__ cis, int* __restrict__ flag) {
    int any = 0;
    for (int i = threadIdx.x; i < 16384; i += 64)
        any |= cis[4 * i + 1];
    #pragma unroll
    for (int off = 1; off < 64; off <<= 1) any |= __shfl_xor(any, off);
    if (threadIdx.x == 0) flag[0] = (any != 0) ? 1 : 0;
}

// ---------------------------------------------------------------------------
// Pack cis[g][s] and mask[b][s] into bit-words (one wave per u64 via ballot).
// ---------------------------------------------------------------------------
__global__ __launch_bounds__(256) void pack_masks(
    const void* __restrict__ cisv, const int* __restrict__ mask,
    const int* __restrict__ flag, u64* __restrict__ cbits, u64* __restrict__ mbits)
{
    const int wid  = blockIdx.x * 4 + (threadIdx.x >> 6);
    const int lane = threadIdx.x & 63;
    if (wid < CIS_WORDS) {
        int v;
        if (flag[0]) v = ((const unsigned char*)cisv)[(size_t)wid * 64 + lane];
        else         v = ((const int*)cisv)[(size_t)wid * 64 + lane];
        const u64 bits = __ballot(v != 0);
        if (lane == 0) cbits[wid] = bits;
    } else if (wid < CIS_WORDS + BATCH * (S_LEN / 64)) {
        const int w2 = wid - CIS_WORDS;               // b*64 + sw
        const u64 bits = __ballot(mask[w2 * 64 + lane] != 0);
        if (lane == 0) mbits[w2] = bits;
    }
}

// ---------------------------------------------------------------------------
// GEMM: Y[m][n] = (sum_k X[m][k]*W[n][k] + bias[n] (+ shift)) * oscale
// ---------------------------------------------------------------------------
template<int A_IS_BF16, int TRANS_OUT, int OUT_F32, int ROWS_PER_B>
__global__ __launch_bounds__(256) void gemm_proj(
    const void* __restrict__ Ap, const float* __restrict__ W,
    const float* __restrict__ bias, const float* __restrict__ shift,
    void* __restrict__ Out, float oscale)
{
    __shared__ bf16 As[64][72];
    __shared__ bf16 Bs[64][72];
    const int tid  = threadIdx.x;
    const int lane = tid & 63;
    const int wave = tid >> 6;
    const int l15  = lane & 15;
    const int l4   = lane >> 4;
    const int m0   = blockIdx.x * 64;
    const int n0   = blockIdx.y * 64;

    f32x4 acc[4] = {};

    for (int kt = 0; kt < DM; kt += 64) {
        #pragma unroll
        for (int i = 0; i < 4; ++i) {
            const int q   = tid + i * 256;
            const int row = q >> 4;
            const int kq  = (q & 15) * 4;
            bf16x4 av;
            if (A_IS_BF16) {
                av = *(const bf16x4*)((const bf16*)Ap + (size_t)(m0 + row) * DM + kt + kq);
            } else {
                const float4 v = *(const float4*)((const float*)Ap + (size_t)(m0 + row) * DM + kt + kq);
                av[0] = (bf16)v.x; av[1] = (bf16)v.y; av[2] = (bf16)v.z; av[3] = (bf16)v.w;
            }
            *(bf16x4*)&As[row][kq] = av;
            const float4 w = *(const float4*)(W + (size_t)(n0 + row) * DM + kt + kq);
            bf16x4 bv;
            bv[0] = (bf16)w.x; bv[1] = (bf16)w.y; bv[2] = (bf16)w.z; bv[3] = (bf16)w.w;
            *(bf16x4*)&Bs[row][kq] = bv;
        }
        __syncthreads();
        #pragma unroll
        for (int ks = 0; ks < 64; ks += 32) {
            const bf16x8 a = *(const bf16x8*)&As[wave * 16 + l15][ks + 8 * l4];
            #pragma unroll
            for (int n = 0; n < 4; ++n) {
                const bf16x8 b = *(const bf16x8*)&Bs[n * 16 + l15][ks + 8 * l4];
                acc[n] = mfma16(a, b, acc[n]);
            }
        }
        __syncthreads();
    }

    #pragma unroll
    for (int n = 0; n < 4; ++n) {
        const int col = n0 + n * 16 + l15;
        const float bv = bias[col];
        #pragma unroll
        for (int r = 0; r < 4; ++r) {
            const int m = m0 + wave * 16 + l4 * 4 + r;
            float v = acc[n][r] + bv;
            if (shift) v += shift[(m / ROWS_PER_B) * DM + col];
            v *= oscale;
            if (TRANS_OUT) {
                ((bf16*)Out)[((size_t)(m / ROWS_PER_B) * DM + col) * ROWS_PER_B + (m % ROWS_PER_B)] = (bf16)v;
            } else if (OUT_F32) {
                ((float*)Out)[(size_t)m * DM + col] = v;
            } else {
                ((bf16*)Out)[(size_t)m * DM + col] = (bf16)v;
            }
        }
    }
}

// ---------------------------------------------------------------------------
// Flash attention, 32x32 MFMA, all-register P path (no LDS in hot loop).
// Block = 32 q-rows, 4 waves splitting S (1024 s each). Grid 1024 blocks.
// QK^T swapped (A=K, B=Q): lane holds q=lane&31, s=(reg&3)+8*(reg>>2)+4*hi.
// P f32 -> bf16 via v_cvt_pk_bf16_f32, redistributed to PV A-frag layout
// (k = 8*hi + j) with 4x v_permlane32_swap_b32:
//   swap(w[0][t], w[1][t]) -> PA[ks0] words jj=t and jj=2+t
//   swap(w[2][t], w[3][t]) -> PA[ks1] words jj=t and jj=2+t
// No max-subtraction (validated rounds 5-7). Merge partials once in LDS.
// Tripwire: WRITE_SIZE ~10MB (spills would explode it; rounds 3/7).
// ---------------------------------------------------------------------------
__global__ __launch_bounds__(256) void attn_kernel(
    const bf16* __restrict__ Qb, const bf16* __restrict__ Kb,
    const bf16* __restrict__ Vt, const u64* __restrict__ mbits,
    const u64* __restrict__ cbits, bf16* __restrict__ AO)
{
    __shared__ __align__(16) float MB[256 + 4 * 32 * 64];  // L[4][64] | ACC[4][32][64]

    const int tid  = threadIdx.x;
    const int lane = tid & 63;
    const int wave = tid >> 6;
    const int l31  = lane & 31;
    const int hi   = lane >> 5;

    // XCD-aware remap (bijective: 1024 = 8 XCD * 4 pairs * 32 q-tiles)
    const int flat = blockIdx.x + 32 * blockIdx.y + 256 * blockIdx.z;
    const int xcd  = flat & 7;
    const int slot = flat >> 3;
    const int pr   = xcd * 4 + (slot >> 5);   // (b,h) pair 0..31
    const int b    = pr >> 3;
    const int h    = pr & 7;
    const int g0   = (slot & 31) * 32;

    // Q B-frags (persistent): q = g0+l31, dk = 16m + 8hi + r  (Q pre-scaled 0.125)
    const bf16* qbase = Qb + (size_t)(b * G_LEN + g0 + l31) * DM + h * DK + 8 * hi;
    const bf16x8 qf0 = *(const bf16x8*)(qbase);
    const bf16x8 qf1 = *(const bf16x8*)(qbase + 16);
    const bf16x8 qf2 = *(const bf16x8*)(qbase + 32);
    const bf16x8 qf3 = *(const bf16x8*)(qbase + 48);

    const bf16* Kbase = Kb + (size_t)b * S_LEN * DM + h * DK;
    const bf16* Vbase = Vt + (size_t)(b * NH + h) * DK * S_LEN;
    const u64*  mbv = mbits + b * (S_LEN / 64);
    const u64*  cbv = cbits + (size_t)(g0 + l31) * (S_LEN / 64);

    f32x16 accA = {};   // d = l31      (half A)
    f32x16 accB = {};   // d = 32 + l31 (half B)
    float lsum = 0.f;

    const int sbeg = wave * (S_LEN / 4);
    for (int s0 = sbeg; s0 < sbeg + S_LEN / 4; s0 += 32) {
        // ---- QK^T: A = K rows (i = s0+l31, k = 16m+8hi+j), chained over dk
        const bf16* krow = Kbase + (size_t)(s0 + l31) * DM + 8 * hi;
        f32x16 c = {};
        c = mfma32(*(const bf16x8*)(krow),      qf0, c);
        c = mfma32(*(const bf16x8*)(krow + 16), qf1, c);
        c = mfma32(*(const bf16x8*)(krow + 32), qf2, c);
        c = mfma32(*(const bf16x8*)(krow + 48), qf3, c);

        // ---- mask word for this lane's q-row; bit s_local = (reg&3)+8*(reg>>2)+4hi
        const int sw = s0 >> 6;
        const u64 w64 = cbv[sw] & mbv[sw];
        const uint32_t kw = ((uint32_t)(w64 >> (s0 & 32))) >> (4 * hi);

        // ---- p = keep ? exp(score) : 0 (no max-sub; lane-local)
        float p[16];
        #pragma unroll
        for (int reg = 0; reg < 16; ++reg) {
            const int bit = (reg & 3) + 8 * (reg >> 2);
            const float e = __expf(c[reg]);
            p[reg] = ((kw >> bit) & 1u) ? e : 0.f;
        }
        lsum += ((p[0] + p[1]) + (p[2] + p[3])) + ((p[4] + p[5]) + (p[6] + p[7]))
              + ((p[8] + p[9]) + (p[10] + p[11])) + ((p[12] + p[13]) + (p[14] + p[15]));

        // ---- P -> bf16 words w[m][t] = pk(p[4m+2t], p[4m+2t+1]); s = 8m+4hi+2t
        uint32_t wa0 = cvtpk(p[0],  p[1]),  wa1 = cvtpk(p[2],  p[3]);
        uint32_t wb0 = cvtpk(p[4],  p[5]),  wb1 = cvtpk(p[6],  p[7]);
        uint32_t wc0 = cvtpk(p[8],  p[9]),  wc1 = cvtpk(p[10], p[11]);
        uint32_t wd0 = cvtpk(p[12], p[13]), wd1 = cvtpk(p[14], p[15]);
        // ---- redistribute to A-frag layout (k = 8hi + j) via permlane32_swap
        pswap(wa0, wb0);   // -> PA[ks0] jj=0 (wa0), jj=2 (wb0)
        pswap(wa1, wb1);   // -> PA[ks0] jj=1 (wa1), jj=3 (wb1)
        pswap(wc0, wd0);   // -> PA[ks1] jj=0, jj=2
        pswap(wc1, wd1);   // -> PA[ks1] jj=1, jj=3
        const bf16x8 pa0 = mk8(wa0, wa1, wb0, wb1);   // s = 8hi + 0..7
        const bf16x8 pa1 = mk8(wc0, wc1, wd0, wd1);   // s = 16 + 8hi + 0..7

        // ---- PV: B = V^T rows (j = d, k = s); two d-halves x two k-steps
        const bf16* va = Vbase + (size_t)l31 * S_LEN + s0 + 8 * hi;
        const bf16* vb = va + (size_t)32 * S_LEN;
        accA = mfma32(pa0, *(const bf16x8*)(va),      accA);
        accA = mfma32(pa1, *(const bf16x8*)(va + 16), accA);
        accB = mfma32(pa0, *(const bf16x8*)(vb),      accB);
        accB = mfma32(pa1, *(const bf16x8*)(vb + 16), accB);
    }

    // ---- merge the 4 S-chunk partials in LDS (once per kernel) ----
    MB[wave * 64 + hi * 32 + l31] = lsum;          // L[wave][hi*32 + q]
    float* accw = MB + 256 + wave * 2048;          // ACC[wave][q][d]
    #pragma unroll
    for (int reg = 0; reg < 16; ++reg) {
        const int q = (reg & 3) + 8 * (reg >> 2) + 4 * hi;
        accw[q * 64 + l31]      = accA[reg];
        accw[q * 64 + 32 + l31] = accB[reg];
    }
    __syncthreads();

    #pragma unroll
    for (int i = 0; i < 8; ++i) {
        const int idx = tid + i * 256;
        const int q = idx >> 6;
        const int d = idx & 63;
        const float o = MB[256 + q * 64 + d] + MB[256 + 2048 + q * 64 + d]
                      + MB[256 + 4096 + q * 64 + d] + MB[256 + 6144 + q * 64 + d];
        float tl = 0.f;
        #pragma unroll
        for (int wv = 0; wv < 4; ++wv) tl += MB[wv * 64 + q] + MB[wv * 64 + 32 + q];
        const float inv = tl > 0.f ? 1.f / tl : 0.f;
        AO[(size_t)(b * G_LEN + g0 + q) * DM + h * DK + d] = (bf16)(o * inv);
    }
}

// ---------------------------------------------------------------------------
// Row LayerNorm: one block per row (512 cols), 256 threads.
// ---------------------------------------------------------------------------
__global__ __launch_bounds__(256) void out_ln(
    const float* __restrict__ Y, const float* __restrict__ gam,
    const float* __restrict__ bet, float* __restrict__ out)
{
    const int row = blockIdx.x;
    const int tid = threadIdx.x;
    const float x0 = Y[(size_t)row * DM + tid];
    const float x1 = Y[(size_t)row * DM + 256 + tid];
    float s  = x0 + x1;
    float sq = x0 * x0 + x1 * x1;
    #pragma unroll
    for (int off = 1; off < 64; off <<= 1) {
        s  += __shfl_xor(s, off);
        sq += __shfl_xor(sq, off);
    }
    __shared__ float ss[4], ssq[4];
    const int wave = tid >> 6;
    if ((tid & 63) == 0) { ss[wave] = s; ssq[wave] = sq; }
    __syncthreads();
    s  = ss[0] + ss[1] + ss[2] + ss[3];
    sq = ssq[0] + ssq[1] + ssq[2] + ssq[3];
    const float mu  = s * (1.f / 512.f);
    const float var = sq * (1.f / 512.f) - mu * mu;
    const float rs  = rsqrtf(var + 1e-5f);
    out[(size_t)row * DM + tid]       = (x0 - mu) * rs * gam[tid] + bet[tid];
    out[(size_t)row * DM + 256 + tid] = (x1 - mu) * rs * gam[tid + 256] + bet[tid + 256];
}

// ---------------------------------------------------------------------------
extern "C" void kernel_launch(void* const* d_in, const int* in_sizes, int n_in,
                              void* d_out, int out_size, void* d_ws, size_t ws_size,
                              hipStream_t stream) {
    const float* queries     = (const float*)d_in[0];   // [4,1024,512]
    const float* keys_values = (const float*)d_in[1];   // [4,4096,512]
    const float* dq          = (const float*)d_in[2];   // [4,1,512]
    const float* dk          = (const float*)d_in[3];   // [4,1,512]
    const int*   mask        = (const int*)d_in[4];     // [4,4096]
    const void*  cis         = d_in[5];                 // [1024,4096] bool (dtype detected)
    const float* wq_w = (const float*)d_in[6];
    const float* wq_b = (const float*)d_in[7];
    const float* wk_w = (const float*)d_in[8];
    const float* wk_b = (const float*)d_in[9];
    const float* wv_w = (const float*)d_in[10];
    const float* wv_b = (const float*)d_in[11];
    const float* wo_w = (const float*)d_in[12];
    const float* wo_b = (const float*)d_in[13];
    const float* ln_g = (const float*)d_in[14];
    const float* ln_b = (const float*)d_in[15];
    float* out = (float*)d_out;

    char* ws = (char*)d_ws;
    bf16*  Qbf = (bf16*)(ws);                                   //  4 MB [4096,512] (pre-scaled x0.125)
    bf16*  Kbf = (bf16*)(ws + (4u << 20));                      // 16 MB [16384,512]
    bf16*  Vt  = (bf16*)(ws + (20u << 20));                     // 16 MB [4,8,64,4096]
    bf16*  AO  = (bf16*)(ws + (36u << 20));                     //  4 MB [4096,512]
    float* Yw  = (float*)(ws + (40u << 20));                    //  8 MB [4096,512]
    int*   cisflag = (int*)(ws + (48u << 20));                  //  4 B
    u64*   mbits   = (u64*)(ws + (48u << 20) + 4096);           //  2 KB [4][64]
    u64*   cbits   = (u64*)(ws + (48u << 20) + 8192);           // 512 KB [1024][64]

    detect_cis<<<1, 64, 0, stream>>>((const unsigned char*)cis, cisflag);
    pack_masks<<<(CIS_WORDS + BATCH * (S_LEN / 64) + 3) / 4, 256, 0, stream>>>(
        cis, mask, cisflag, cbits, mbits);

    // Projections. Q pre-scaled by 1/sqrt(d_k)=0.125 (exact pow2, folded here).
    gemm_proj<0, 0, 0, 1024><<<dim3(64, 8),  256, 0, stream>>>(queries,     wq_w, wq_b, dq,      Qbf, 0.125f);
    gemm_proj<0, 0, 0, 4096><<<dim3(256, 8), 256, 0, stream>>>(keys_values, wk_w, wk_b, dk,      Kbf, 1.0f);
    gemm_proj<0, 1, 0, 4096><<<dim3(256, 8), 256, 0, stream>>>(keys_values, wv_w, wv_b, nullptr, Vt,  1.0f);

    // Fused masked flash attention (32x32 MFMA, register-only P path)
    attn_kernel<<<dim3(32, 8, 4), 256, 0, stream>>>(Qbf, Kbf, Vt, mbits, cbits, AO);

    // Output projection (bf16 A) -> f32 scratch
    gemm_proj<1, 0, 1, 1024><<<dim3(64, 8),  256, 0, stream>>>(AO, wo_w, wo_b, nullptr, Yw, 1.0f);

    // LayerNorm -> d_out
    out_ln<<<4096, 256, 0, stream>>>(Yw, ln_g, ln_b, out);
}

// Round 9
// 302.799 us; speedup vs baseline: 1.5508x; 1.0293x over previous
//
#include <hip/hip_runtime.h>
#include <stdint.h>
#include <stddef.h>

typedef __bf16 bf16;
typedef __bf16 bf16x4 __attribute__((ext_vector_type(4)));
typedef __bf16 bf16x8 __attribute__((ext_vector_type(8)));
typedef float f32x4 __attribute__((ext_vector_type(4)));
typedef float f32x16 __attribute__((ext_vector_type(16)));
typedef unsigned long long u64;

#define BATCH 4
#define G_LEN 1024
#define S_LEN 4096
#define DM 512
#define NH 8
#define DK 64
#define CIS_WORDS (G_LEN * (S_LEN / 64))   // 65536

__device__ __forceinline__ f32x4 mfma16(bf16x8 a, bf16x8 b, f32x4 c) {
    return __builtin_amdgcn_mfma_f32_16x16x32_bf16(a, b, c, 0, 0, 0);
}
__device__ __forceinline__ f32x16 mfma32(bf16x8 a, bf16x8 b, f32x16 c) {
    return __builtin_amdgcn_mfma_f32_32x32x16_bf16(a, b, c, 0, 0, 0);
}
// v_cvt_pk_bf16_f32: dst.lo = bf16(lo), dst.hi = bf16(hi). No builtin (m240).
__device__ __forceinline__ uint32_t cvtpk(float lo, float hi_) {
    uint32_t r;
    asm("v_cvt_pk_bf16_f32 %0, %1, %2" : "=v"(r) : "v"(lo), "v"(hi_));
    return r;
}
// v_permlane32_swap_b32: a.lanes[32:64] <-> b.lanes[0:32] (gfx950).
__device__ __forceinline__ void pswap(uint32_t& a, uint32_t& b) {
    asm("v_permlane32_swap_b32 %0, %1" : "+v"(a), "+v"(b));
}
__device__ __forceinline__ bf16x8 mk8(uint32_t a, uint32_t b, uint32_t c, uint32_t d) {
    union { uint32_t u[4]; bf16x8 v; } x;
    x.u[0] = a; x.u[1] = b; x.u[2] = c; x.u[3] = d;
    return x.v;
}

// ---------------------------------------------------------------------------
// cis dtype detection (bool vs int32) — see round 1 notes. flag=1 -> bytes.
// ---------------------------------------------------------------------------
__global__ void detect_cis(const unsigned char* __restrict__ cis, int* __restrict__ flag) {
    int any = 0;
    for (int i = threadIdx.x; i < 16384; i += 64)
        any |= cis[4 * i + 1];
    #pragma unroll
    for (int off = 1; off < 64; off <<= 1) any |= __shfl_xor(any, off);
    if (threadIdx.x == 0) flag[0] = (any != 0) ? 1 : 0;
}

// ---------------------------------------------------------------------------
// Pack cis[g][s] and mask[b][s] into bit-words (one wave per u64 via ballot).
// ---------------------------------------------------------------------------
__global__ __launch_bounds__(256) void pack_masks(
    const void* __restrict__ cisv, const int* __restrict__ mask,
    const int* __restrict__ flag, u64* __restrict__ cbits, u64* __restrict__ mbits)
{
    const int wid  = blockIdx.x * 4 + (threadIdx.x >> 6);
    const int lane = threadIdx.x & 63;
    if (wid < CIS_WORDS) {
        int v;
        if (flag[0]) v = ((const unsigned char*)cisv)[(size_t)wid * 64 + lane];
        else         v = ((const int*)cisv)[(size_t)wid * 64 + lane];
        const u64 bits = __ballot(v != 0);
        if (lane == 0) cbits[wid] = bits;
    } else if (wid < CIS_WORDS + BATCH * (S_LEN / 64)) {
        const int w2 = wid - CIS_WORDS;               // b*64 + sw
        const u64 bits = __ballot(mask[w2 * 64 + lane] != 0);
        if (lane == 0) mbits[w2] = bits;
    }
}

// ---------------------------------------------------------------------------
// GEMM: Y[m][n] = (sum_k X[m][k]*W[n][k] + bias[n] (+ shift)) * oscale
// ---------------------------------------------------------------------------
template<int A_IS_BF16, int TRANS_OUT, int OUT_F32, int ROWS_PER_B>
__global__ __launch_bounds__(256) void gemm_proj(
    const void* __restrict__ Ap, const float* __restrict__ W,
    const float* __restrict__ bias, const float* __restrict__ shift,
    void* __restrict__ Out, float oscale)
{
    __shared__ bf16 As[64][72];
    __shared__ bf16 Bs[64][72];
    const int tid  = threadIdx.x;
    const int lane = tid & 63;
    const int wave = tid >> 6;
    const int l15  = lane & 15;
    const int l4   = lane >> 4;
    const int m0   = blockIdx.x * 64;
    const int n0   = blockIdx.y * 64;

    f32x4 acc[4] = {};

    for (int kt = 0; kt < DM; kt += 64) {
        #pragma unroll
        for (int i = 0; i < 4; ++i) {
            const int q   = tid + i * 256;
            const int row = q >> 4;
            const int kq  = (q & 15) * 4;
            bf16x4 av;
            if (A_IS_BF16) {
                av = *(const bf16x4*)((const bf16*)Ap + (size_t)(m0 + row) * DM + kt + kq);
            } else {
                const float4 v = *(const float4*)((const float*)Ap + (size_t)(m0 + row) * DM + kt + kq);
                av[0] = (bf16)v.x; av[1] = (bf16)v.y; av[2] = (bf16)v.z; av[3] = (bf16)v.w;
            }
            *(bf16x4*)&As[row][kq] = av;
            const float4 w = *(const float4*)(W + (size_t)(n0 + row) * DM + kt + kq);
            bf16x4 bv;
            bv[0] = (bf16)w.x; bv[1] = (bf16)w.y; bv[2] = (bf16)w.z; bv[3] = (bf16)w.w;
            *(bf16x4*)&Bs[row][kq] = bv;
        }
        __syncthreads();
        #pragma unroll
        for (int ks = 0; ks < 64; ks += 32) {
            const bf16x8 a = *(const bf16x8*)&As[wave * 16 + l15][ks + 8 * l4];
            #pragma unroll
            for (int n = 0; n < 4; ++n) {
                const bf16x8 b = *(const bf16x8*)&Bs[n * 16 + l15][ks + 8 * l4];
                acc[n] = mfma16(a, b, acc[n]);
            }
        }
        __syncthreads();
    }

    #pragma unroll
    for (int n = 0; n < 4; ++n) {
        const int col = n0 + n * 16 + l15;
        const float bv = bias[col];
        #pragma unroll
        for (int r = 0; r < 4; ++r) {
            const int m = m0 + wave * 16 + l4 * 4 + r;
            float v = acc[n][r] + bv;
            if (shift) v += shift[(m / ROWS_PER_B) * DM + col];
            v *= oscale;
            if (TRANS_OUT) {
                ((bf16*)Out)[((size_t)(m / ROWS_PER_B) * DM + col) * ROWS_PER_B + (m % ROWS_PER_B)] = (bf16)v;
            } else if (OUT_F32) {
                ((float*)Out)[(size_t)m * DM + col] = v;
            } else {
                ((bf16*)Out)[(size_t)m * DM + col] = (bf16)v;
            }
        }
    }
}

// ---------------------------------------------------------------------------
// Flash attention, 32x32 MFMA, register-only P path, software-pipelined:
// K fragments double-buffered in registers (prefetch tile t+1 while computing
// t); V loads issued at iteration top (~300cy ahead of PV use). Round-8 stall
// analysis: per-tile chain was headed by ~500cy unhidden L2 load latency.
// Tail prefetch reads <=64KB past K buffer into Vt region (mapped, unused).
// Tripwire: WRITE_SIZE ~4MB (spills would explode it).
// ---------------------------------------------------------------------------
__global__ __launch_bounds__(256) void attn_kernel(
    const bf16* __restrict__ Qb, const bf16* __restrict__ Kb,
    const bf16* __restrict__ Vt, const u64* __restrict__ mbits,
    const u64* __restrict__ cbits, bf16* __restrict__ AO)
{
    __shared__ __align__(16) float MB[256 + 4 * 32 * 64];  // L[4][64] | ACC[4][32][64]

    const int tid  = threadIdx.x;
    const int lane = tid & 63;
    const int wave = tid >> 6;
    const int l31  = lane & 31;
    const int hi   = lane >> 5;

    // XCD-aware remap (bijective: 1024 = 8 XCD * 4 pairs * 32 q-tiles)
    const int flat = blockIdx.x + 32 * blockIdx.y + 256 * blockIdx.z;
    const int xcd  = flat & 7;
    const int slot = flat >> 3;
    const int pr   = xcd * 4 + (slot >> 5);   // (b,h) pair 0..31
    const int b    = pr >> 3;
    const int h    = pr & 7;
    const int g0   = (slot & 31) * 32;

    // Q B-frags (persistent): q = g0+l31, dk = 16m + 8hi + r  (Q pre-scaled 0.125)
    const bf16* qbase = Qb + (size_t)(b * G_LEN + g0 + l31) * DM + h * DK + 8 * hi;
    const bf16x8 qf0 = *(const bf16x8*)(qbase);
    const bf16x8 qf1 = *(const bf16x8*)(qbase + 16);
    const bf16x8 qf2 = *(const bf16x8*)(qbase + 32);
    const bf16x8 qf3 = *(const bf16x8*)(qbase + 48);

    const bf16* Kbase = Kb + (size_t)b * S_LEN * DM + h * DK;
    const bf16* Vbase = Vt + (size_t)(b * NH + h) * DK * S_LEN;
    const u64*  mbv = mbits + b * (S_LEN / 64);
    const u64*  cbv = cbits + (size_t)(g0 + l31) * (S_LEN / 64);

    f32x16 accA = {};   // d = l31      (half A)
    f32x16 accB = {};   // d = 32 + l31 (half B)
    float lsum = 0.f;

    const int sbeg = wave * (S_LEN / 4);
    const int send = sbeg + S_LEN / 4;

    // ---- prologue: K fragments for first tile
    const bf16* kr0 = Kbase + (size_t)(sbeg + l31) * DM + 8 * hi;
    bf16x8 kc0 = *(const bf16x8*)(kr0);
    bf16x8 kc1 = *(const bf16x8*)(kr0 + 16);
    bf16x8 kc2 = *(const bf16x8*)(kr0 + 32);
    bf16x8 kc3 = *(const bf16x8*)(kr0 + 48);

    for (int s0 = sbeg; s0 < send; s0 += 32) {
        // ---- V loads for current tile: issued ~300cy before PV needs them
        const bf16* va = Vbase + (size_t)l31 * S_LEN + s0 + 8 * hi;
        const bf16* vb = va + (size_t)32 * S_LEN;
        const bf16x8 v0 = *(const bf16x8*)(va);
        const bf16x8 v1 = *(const bf16x8*)(va + 16);
        const bf16x8 v2 = *(const bf16x8*)(vb);
        const bf16x8 v3 = *(const bf16x8*)(vb + 16);

        // ---- K prefetch for next tile (consumed next iteration)
        const bf16* krn = Kbase + (size_t)(s0 + 32 + l31) * DM + 8 * hi;
        const bf16x8 kn0 = *(const bf16x8*)(krn);
        const bf16x8 kn1 = *(const bf16x8*)(krn + 16);
        const bf16x8 kn2 = *(const bf16x8*)(krn + 32);
        const bf16x8 kn3 = *(const bf16x8*)(krn + 48);

        // ---- QK^T with current K (already resident since last iteration)
        f32x16 c = {};
        c = mfma32(kc0, qf0, c);
        c = mfma32(kc1, qf1, c);
        c = mfma32(kc2, qf2, c);
        c = mfma32(kc3, qf3, c);

        // ---- mask word; bit s_local = (reg&3)+8*(reg>>2)+4hi
        const int sw = s0 >> 6;
        const u64 w64 = cbv[sw] & mbv[sw];
        const uint32_t kw = ((uint32_t)(w64 >> (s0 & 32))) >> (4 * hi);

        // ---- p = keep ? exp(score) : 0, in place (saves 16 VGPR)
        #pragma unroll
        for (int reg = 0; reg < 16; ++reg) {
            const int bit = (reg & 3) + 8 * (reg >> 2);
            const float e = __expf(c[reg]);
            c[reg] = ((kw >> bit) & 1u) ? e : 0.f;
        }
        lsum += ((c[0] + c[1]) + (c[2] + c[3])) + ((c[4] + c[5]) + (c[6] + c[7]))
              + ((c[8] + c[9]) + (c[10] + c[11])) + ((c[12] + c[13]) + (c[14] + c[15]));

        // ---- pack to bf16 + permlane redistribute to PV A-frag layout
        uint32_t wa0 = cvtpk(c[0],  c[1]),  wa1 = cvtpk(c[2],  c[3]);
        uint32_t wb0 = cvtpk(c[4],  c[5]),  wb1 = cvtpk(c[6],  c[7]);
        uint32_t wc0 = cvtpk(c[8],  c[9]),  wc1 = cvtpk(c[10], c[11]);
        uint32_t wd0 = cvtpk(c[12], c[13]), wd1 = cvtpk(c[14], c[15]);
        pswap(wa0, wb0);
        pswap(wa1, wb1);
        pswap(wc0, wd0);
        pswap(wc1, wd1);
        const bf16x8 pa0 = mk8(wa0, wa1, wb0, wb1);   // s = 8hi + 0..7
        const bf16x8 pa1 = mk8(wc0, wc1, wd0, wd1);   // s = 16 + 8hi + 0..7

        // ---- PV (V loads issued at top; latency hidden under QK/exp/pack)
        accA = mfma32(pa0, v0, accA);
        accA = mfma32(pa1, v1, accA);
        accB = mfma32(pa0, v2, accB);
        accB = mfma32(pa1, v3, accB);

        // ---- rotate K double-buffer
        kc0 = kn0; kc1 = kn1; kc2 = kn2; kc3 = kn3;
    }

    // ---- merge the 4 S-chunk partials in LDS (once per kernel) ----
    MB[wave * 64 + hi * 32 + l31] = lsum;          // L[wave][hi*32 + q]
    float* accw = MB + 256 + wave * 2048;          // ACC[wave][q][d]
    #pragma unroll
    for (int reg = 0; reg < 16; ++reg) {
        const int q = (reg & 3) + 8 * (reg >> 2) + 4 * hi;
        accw[q * 64 + l31]      = accA[reg];
        accw[q * 64 + 32 + l31] = accB[reg];
    }
    __syncthreads();

    #pragma unroll
    for (int i = 0; i < 8; ++i) {
        const int idx = tid + i * 256;
        const int q = idx >> 6;
        const int d = idx & 63;
        const float o = MB[256 + q * 64 + d] + MB[256 + 2048 + q * 64 + d]
                      + MB[256 + 4096 + q * 64 + d] + MB[256 + 6144 + q * 64 + d];
        float tl = 0.f;
        #pragma unroll
        for (int wv = 0; wv < 4; ++wv) tl += MB[wv * 64 + q] + MB[wv * 64 + 32 + q];
        const float inv = tl > 0.f ? 1.f / tl : 0.f;
        AO[(size_t)(b * G_LEN + g0 + q) * DM + h * DK + d] = (bf16)(o * inv);
    }
}

// ---------------------------------------------------------------------------
// Row LayerNorm: one block per row (512 cols), 256 threads.
// ---------------------------------------------------------------------------
__global__ __launch_bounds__(256) void out_ln(
    const float* __restrict__ Y, const float* __restrict__ gam,
    const float* __restrict__ bet, float* __restrict__ out)
{
    const int row = blockIdx.x;
    const int tid = threadIdx.x;
    const float x0 = Y[(size_t)row * DM + tid];
    const float x1 = Y[(size_t)row * DM + 256 + tid];
    float s  = x0 + x1;
    float sq = x0 * x0 + x1 * x1;
    #pragma unroll
    for (int off = 1; off < 64; off <<= 1) {
        s  += __shfl_xor(s, off);
        sq += __shfl_xor(sq, off);
    }
    __shared__ float ss[4], ssq[4];
    const int wave = tid >> 6;
    if ((tid & 63) == 0) { ss[wave] = s; ssq[wave] = sq; }
    __syncthreads();
    s  = ss[0] + ss[1] + ss[2] + ss[3];
    sq = ssq[0] + ssq[1] + ssq[2] + ssq[3];
    const float mu  = s * (1.f / 512.f);
    const float var = sq * (1.f / 512.f) - mu * mu;
    const float rs  = rsqrtf(var + 1e-5f);
    out[(size_t)row * DM + tid]       = (x0 - mu) * rs * gam[tid] + bet[tid];
    out[(size_t)row * DM + 256 + tid] = (x1 - mu) * rs * gam[tid + 256] + bet[tid + 256];
}

// ---------------------------------------------------------------------------
extern "C" void kernel_launch(void* const* d_in, const int* in_sizes, int n_in,
                              void* d_out, int out_size, void* d_ws, size_t ws_size,
                              hipStream_t stream) {
    const float* queries     = (const float*)d_in[0];   // [4,1024,512]
    const float* keys_values = (const float*)d_in[1];   // [4,4096,512]
    const float* dq          = (const float*)d_in[2];   // [4,1,512]
    const float* dk          = (const float*)d_in[3];   // [4,1,512]
    const int*   mask        = (const int*)d_in[4];     // [4,4096]
    const void*  cis         = d_in[5];                 // [1024,4096] bool (dtype detected)
    const float* wq_w = (const float*)d_in[6];
    const float* wq_b = (const float*)d_in[7];
    const float* wk_w = (const float*)d_in[8];
    const float* wk_b = (const float*)d_in[9];
    const float* wv_w = (const float*)d_in[10];
    const float* wv_b = (const float*)d_in[11];
    const float* wo_w = (const float*)d_in[12];
    const float* wo_b = (const float*)d_in[13];
    const float* ln_g = (const float*)d_in[14];
    const float* ln_b = (const float*)d_in[15];
    float* out = (float*)d_out;

    char* ws = (char*)d_ws;
    bf16*  Qbf = (bf16*)(ws);                                   //  4 MB [4096,512] (pre-scaled x0.125)
    bf16*  Kbf = (bf16*)(ws + (4u << 20));                      // 16 MB [16384,512]
    bf16*  Vt  = (bf16*)(ws + (20u << 20));                     // 16 MB [4,8,64,4096]
    bf16*  AO  = (bf16*)(ws + (36u << 20));                     //  4 MB [4096,512]
    float* Yw  = (float*)(ws + (40u << 20));                    //  8 MB [4096,512]
    int*   cisflag = (int*)(ws + (48u << 20));                  //  4 B
    u64*   mbits   = (u64*)(ws + (48u << 20) + 4096);           //  2 KB [4][64]
    u64*   cbits   = (u64*)(ws + (48u << 20) + 8192);           // 512 KB [1024][64]

    detect_cis<<<1, 64, 0, stream>>>((const unsigned char*)cis, cisflag);
    pack_masks<<<(CIS_WORDS + BATCH * (S_LEN / 64) + 3) / 4, 256, 0, stream>>>(
        cis, mask, cisflag, cbits, mbits);

    // Projections. Q pre-scaled by 1/sqrt(d_k)=0.125 (exact pow2, folded here).
    gemm_proj<0, 0, 0, 1024><<<dim3(64, 8),  256, 0, stream>>>(queries,     wq_w, wq_b, dq,      Qbf, 0.125f);
    gemm_proj<0, 0, 0, 4096><<<dim3(256, 8), 256, 0, stream>>>(keys_values, wk_w, wk_b, dk,      Kbf, 1.0f);
    gemm_proj<0, 1, 0, 4096><<<dim3(256, 8), 256, 0, stream>>>(keys_values, wv_w, wv_b, nullptr, Vt,  1.0f);

    // Fused masked flash attention (32x32 MFMA, reg-only P, K-prefetch pipeline)
    attn_kernel<<<dim3(32, 8, 4), 256, 0, stream>>>(Qbf, Kbf, Vt, mbits, cbits, AO);

    // Output projection (bf16 A) -> f32 scratch
    gemm_proj<1, 0, 1, 1024><<<dim3(64, 8),  256, 0, stream>>>(AO, wo_w, wo_b, nullptr, Yw, 1.0f);

    // LayerNorm -> d_out
    out_ln<<<4096, 256, 0, stream>>>(Yw, ln_g, ln_b, out);
}

// Round 10
// 289.082 us; speedup vs baseline: 1.6244x; 1.0475x over previous
//
#include <hip/hip_runtime.h>
#include <stdint.h>
#include <stddef.h>

typedef __bf16 bf16;
typedef __bf16 bf16x4 __attribute__((ext_vector_type(4)));
typedef __bf16 bf16x8 __attribute__((ext_vector_type(8)));
typedef float f32x4 __attribute__((ext_vector_type(4)));
typedef float f32x16 __attribute__((ext_vector_type(16)));
typedef unsigned long long u64;

#define BATCH 4
#define G_LEN 1024
#define S_LEN 4096
#define DM 512
#define NH 8
#define DK 64
#define CIS_WORDS (G_LEN * (S_LEN / 64))   // 65536

__device__ __forceinline__ f32x4 mfma16(bf16x8 a, bf16x8 b, f32x4 c) {
    return __builtin_amdgcn_mfma_f32_16x16x32_bf16(a, b, c, 0, 0, 0);
}
__device__ __forceinline__ f32x16 mfma32(bf16x8 a, bf16x8 b, f32x16 c) {
    return __builtin_amdgcn_mfma_f32_32x32x16_bf16(a, b, c, 0, 0, 0);
}
// v_cvt_pk_bf16_f32: dst.lo = bf16(lo), dst.hi = bf16(hi). No builtin (m240).
__device__ __forceinline__ uint32_t cvtpk(float lo, float hi_) {
    uint32_t r;
    asm("v_cvt_pk_bf16_f32 %0, %1, %2" : "=v"(r) : "v"(lo), "v"(hi_));
    return r;
}
// v_permlane32_swap_b32: a.lanes[32:64] <-> b.lanes[0:32] (gfx950).
__device__ __forceinline__ void pswap(uint32_t& a, uint32_t& b) {
    asm("v_permlane32_swap_b32 %0, %1" : "+v"(a), "+v"(b));
}
__device__ __forceinline__ bf16x8 mk8(uint32_t a, uint32_t b, uint32_t c, uint32_t d) {
    union { uint32_t u[4]; bf16x8 v; } x;
    x.u[0] = a; x.u[1] = b; x.u[2] = c; x.u[3] = d;
    return x.v;
}
// masked exp + bf16 pack + permlane redistribute into PV A-fragments.
__device__ __forceinline__ void exppack(f32x16& c, uint32_t kw, float& lsum,
                                        bf16x8& pa0, bf16x8& pa1) {
    #pragma unroll
    for (int reg = 0; reg < 16; ++reg) {
        const int bit = (reg & 3) + 8 * (reg >> 2);
        const float e = __expf(c[reg]);
        c[reg] = ((kw >> bit) & 1u) ? e : 0.f;
    }
    lsum += ((c[0] + c[1]) + (c[2] + c[3])) + ((c[4] + c[5]) + (c[6] + c[7]))
          + ((c[8] + c[9]) + (c[10] + c[11])) + ((c[12] + c[13]) + (c[14] + c[15]));
    uint32_t wa0 = cvtpk(c[0],  c[1]),  wa1 = cvtpk(c[2],  c[3]);
    uint32_t wb0 = cvtpk(c[4],  c[5]),  wb1 = cvtpk(c[6],  c[7]);
    uint32_t wc0 = cvtpk(c[8],  c[9]),  wc1 = cvtpk(c[10], c[11]);
    uint32_t wd0 = cvtpk(c[12], c[13]), wd1 = cvtpk(c[14], c[15]);
    pswap(wa0, wb0); pswap(wa1, wb1); pswap(wc0, wd0); pswap(wc1, wd1);
    pa0 = mk8(wa0, wa1, wb0, wb1);   // s = 8hi + 0..7
    pa1 = mk8(wc0, wc1, wd0, wd1);   // s = 16 + 8hi + 0..7
}

// ---------------------------------------------------------------------------
// cis dtype detection (bool vs int32) — see round 1 notes. flag=1 -> bytes.
// ---------------------------------------------------------------------------
__global__ void detect_cis(const unsigned char* __restrict__ cis, int* __restrict__ flag) {
    int any = 0;
    for (int i = threadIdx.x; i < 16384; i += 64)
        any |= cis[4 * i + 1];
    #pragma unroll
    for (int off = 1; off < 64; off <<= 1) any |= __shfl_xor(any, off);
    if (threadIdx.x == 0) flag[0] = (any != 0) ? 1 : 0;
}

// ---------------------------------------------------------------------------
// Pack cis[g][s] and mask[b][s] into bit-words (one wave per u64 via ballot).
// ---------------------------------------------------------------------------
__global__ __launch_bounds__(256) void pack_masks(
    const void* __restrict__ cisv, const int* __restrict__ mask,
    const int* __restrict__ flag, u64* __restrict__ cbits, u64* __restrict__ mbits)
{
    const int wid  = blockIdx.x * 4 + (threadIdx.x >> 6);
    const int lane = threadIdx.x & 63;
    if (wid < CIS_WORDS) {
        int v;
        if (flag[0]) v = ((const unsigned char*)cisv)[(size_t)wid * 64 + lane];
        else         v = ((const int*)cisv)[(size_t)wid * 64 + lane];
        const u64 bits = __ballot(v != 0);
        if (lane == 0) cbits[wid] = bits;
    } else if (wid < CIS_WORDS + BATCH * (S_LEN / 64)) {
        const int w2 = wid - CIS_WORDS;               // b*64 + sw
        const u64 bits = __ballot(mask[w2 * 64 + lane] != 0);
        if (lane == 0) mbits[w2] = bits;
    }
}

// ---------------------------------------------------------------------------
// GEMM: Y[m][n] = (sum_k X[m][k]*W[n][k] + bias[n] (+ shift)) * oscale
// Used for Q-proj (f32 in, bf16 out, x0.125) and O-proj (bf16 in, f32 out).
// ---------------------------------------------------------------------------
template<int A_IS_BF16, int OUT_F32, int ROWS_PER_B>
__global__ __launch_bounds__(256) void gemm_proj(
    const void* __restrict__ Ap, const float* __restrict__ W,
    const float* __restrict__ bias, const float* __restrict__ shift,
    void* __restrict__ Out, float oscale)
{
    __shared__ bf16 As[64][72];
    __shared__ bf16 Bs[64][72];
    const int tid  = threadIdx.x;
    const int lane = tid & 63;
    const int wave = tid >> 6;
    const int l15  = lane & 15;
    const int l4   = lane >> 4;
    const int m0   = blockIdx.x * 64;
    const int n0   = blockIdx.y * 64;

    f32x4 acc[4] = {};

    for (int kt = 0; kt < DM; kt += 64) {
        #pragma unroll
        for (int i = 0; i < 4; ++i) {
            const int q   = tid + i * 256;
            const int row = q >> 4;
            const int kq  = (q & 15) * 4;
            bf16x4 av;
            if (A_IS_BF16) {
                av = *(const bf16x4*)((const bf16*)Ap + (size_t)(m0 + row) * DM + kt + kq);
            } else {
                const float4 v = *(const float4*)((const float*)Ap + (size_t)(m0 + row) * DM + kt + kq);
                av[0] = (bf16)v.x; av[1] = (bf16)v.y; av[2] = (bf16)v.z; av[3] = (bf16)v.w;
            }
            *(bf16x4*)&As[row][kq] = av;
            const float4 w = *(const float4*)(W + (size_t)(n0 + row) * DM + kt + kq);
            bf16x4 bv;
            bv[0] = (bf16)w.x; bv[1] = (bf16)w.y; bv[2] = (bf16)w.z; bv[3] = (bf16)w.w;
            *(bf16x4*)&Bs[row][kq] = bv;
        }
        __syncthreads();
        #pragma unroll
        for (int ks = 0; ks < 64; ks += 32) {
            const bf16x8 a = *(const bf16x8*)&As[wave * 16 + l15][ks + 8 * l4];
            #pragma unroll
            for (int n = 0; n < 4; ++n) {
                const bf16x8 b = *(const bf16x8*)&Bs[n * 16 + l15][ks + 8 * l4];
                acc[n] = mfma16(a, b, acc[n]);
            }
        }
        __syncthreads();
    }

    #pragma unroll
    for (int n = 0; n < 4; ++n) {
        const int col = n0 + n * 16 + l15;
        const float bv = bias[col];
        #pragma unroll
        for (int r = 0; r < 4; ++r) {
            const int m = m0 + wave * 16 + l4 * 4 + r;
            float v = acc[n][r] + bv;
            if (shift) v += shift[(m / ROWS_PER_B) * DM + col];
            v *= oscale;
            if (OUT_F32) ((float*)Out)[(size_t)m * DM + col] = v;
            else         ((bf16*)Out)[(size_t)m * DM + col] = (bf16)v;
        }
    }
}

// ---------------------------------------------------------------------------
// Fused K+V projection: both GEMMs read the same A (keys_values). Stage A
// once, hold two B tiles, 8 MFMAs per K-step. K written [m][col] (+dk shift);
// V written transposed per-batch Vt[b][col][s].
// ---------------------------------------------------------------------------
__global__ __launch_bounds__(256) void gemm_kv(
    const float* __restrict__ X, const float* __restrict__ Wk,
    const float* __restrict__ bk, const float* __restrict__ dkv,
    const float* __restrict__ Wv, const float* __restrict__ bv,
    bf16* __restrict__ OutK, bf16* __restrict__ OutVt)
{
    __shared__ bf16 As[64][72];
    __shared__ bf16 Bk[64][72];
    __shared__ bf16 Bv[64][72];
    const int tid  = threadIdx.x;
    const int lane = tid & 63;
    const int wave = tid >> 6;
    const int l15  = lane & 15;
    const int l4   = lane >> 4;
    const int m0   = blockIdx.x * 64;
    const int n0   = blockIdx.y * 64;

    f32x4 ak[4] = {}, av[4] = {};

    for (int kt = 0; kt < DM; kt += 64) {
        #pragma unroll
        for (int i = 0; i < 4; ++i) {
            const int q   = tid + i * 256;
            const int row = q >> 4;
            const int kq  = (q & 15) * 4;
            const float4 x = *(const float4*)(X  + (size_t)(m0 + row) * DM + kt + kq);
            const float4 k = *(const float4*)(Wk + (size_t)(n0 + row) * DM + kt + kq);
            const float4 v = *(const float4*)(Wv + (size_t)(n0 + row) * DM + kt + kq);
            bf16x4 xa, ka, va;
            xa[0] = (bf16)x.x; xa[1] = (bf16)x.y; xa[2] = (bf16)x.z; xa[3] = (bf16)x.w;
            ka[0] = (bf16)k.x; ka[1] = (bf16)k.y; ka[2] = (bf16)k.z; ka[3] = (bf16)k.w;
            va[0] = (bf16)v.x; va[1] = (bf16)v.y; va[2] = (bf16)v.z; va[3] = (bf16)v.w;
            *(bf16x4*)&As[row][kq] = xa;
            *(bf16x4*)&Bk[row][kq] = ka;
            *(bf16x4*)&Bv[row][kq] = va;
        }
        __syncthreads();
        #pragma unroll
        for (int ks = 0; ks < 64; ks += 32) {
            const bf16x8 a = *(const bf16x8*)&As[wave * 16 + l15][ks + 8 * l4];
            #pragma unroll
            for (int n = 0; n < 4; ++n) {
                const bf16x8 bkf = *(const bf16x8*)&Bk[n * 16 + l15][ks + 8 * l4];
                const bf16x8 bvf = *(const bf16x8*)&Bv[n * 16 + l15][ks + 8 * l4];
                ak[n] = mfma16(a, bkf, ak[n]);
                av[n] = mfma16(a, bvf, av[n]);
            }
        }
        __syncthreads();
    }

    #pragma unroll
    for (int n = 0; n < 4; ++n) {
        const int col = n0 + n * 16 + l15;
        const float bkc = bk[col];
        const float bvc = bv[col];
        #pragma unroll
        for (int r = 0; r < 4; ++r) {
            const int m  = m0 + wave * 16 + l4 * 4 + r;
            const int bb = m >> 12;                 // batch = m / 4096
            OutK[(size_t)m * DM + col] = (bf16)(ak[n][r] + bkc + dkv[bb * DM + col]);
            OutVt[((size_t)bb * DM + col) * 4096 + (m & 4095)] = (bf16)(av[n][r] + bvc);
        }
    }
}

// ---------------------------------------------------------------------------
// Flash attention, 32x32 MFMA, register-only P, 2-stage pipeline:
// PV of tile t-1 runs between QK(t) and exppack(t) — the two MFMA groups are
// independent, so exppack(t) waits out QK's latency under PV issue. K 1-ahead
// prefetch; V loaded at iteration top, consumed next iteration (rotating pair).
// Round-9 model: VALU work (~40us/CU) matched VALUBusy 27% — kernel is chain-
// stalled, not issue-bound. Tripwire: WRITE_SIZE ~4MB (spills).
// ---------------------------------------------------------------------------
__global__ __launch_bounds__(256) void attn_kernel(
    const bf16* __restrict__ Qb, const bf16* __restrict__ Kb,
    const bf16* __restrict__ Vt, const u64* __restrict__ mbits,
    const u64* __restrict__ cbits, bf16* __restrict__ AO)
{
    __shared__ __align__(16) float MB[256 + 4 * 32 * 64];  // L[4][64] | ACC[4][32][64]

    const int tid  = threadIdx.x;
    const int lane = tid & 63;
    const int wave = tid >> 6;
    const int l31  = lane & 31;
    const int hi   = lane >> 5;

    // XCD-aware remap (bijective: 1024 = 8 XCD * 4 pairs * 32 q-tiles)
    const int flat = blockIdx.x + 32 * blockIdx.y + 256 * blockIdx.z;
    const int xcd  = flat & 7;
    const int slot = flat >> 3;
    const int pr   = xcd * 4 + (slot >> 5);   // (b,h) pair 0..31
    const int b    = pr >> 3;
    const int h    = pr & 7;
    const int g0   = (slot & 31) * 32;

    // Q B-frags (persistent): q = g0+l31, dk = 16m + 8hi + r  (Q pre-scaled 0.125)
    const bf16* qbase = Qb + (size_t)(b * G_LEN + g0 + l31) * DM + h * DK + 8 * hi;
    const bf16x8 qf0 = *(const bf16x8*)(qbase);
    const bf16x8 qf1 = *(const bf16x8*)(qbase + 16);
    const bf16x8 qf2 = *(const bf16x8*)(qbase + 32);
    const bf16x8 qf3 = *(const bf16x8*)(qbase + 48);

    const bf16* Kbase = Kb + (size_t)b * S_LEN * DM + h * DK;
    const bf16* Vbase = Vt + (size_t)(b * NH + h) * DK * S_LEN;
    const u64*  mbv = mbits + b * (S_LEN / 64);
    const u64*  cbv = cbits + (size_t)(g0 + l31) * (S_LEN / 64);

    f32x16 accA = {};   // d = l31
    f32x16 accB = {};   // d = 32 + l31
    float lsum = 0.f;

    const int sbeg = wave * (S_LEN / 4);
    const bf16* kp = Kbase + (size_t)(sbeg + l31) * DM + 8 * hi;
    const bf16* vp = Vbase + (size_t)l31 * S_LEN + sbeg + 8 * hi;
    const bf16* vq = vp + (size_t)32 * S_LEN;

    // ---- prologue: tile 0
    bf16x8 kc0 = *(const bf16x8*)(kp);
    bf16x8 kc1 = *(const bf16x8*)(kp + 16);
    bf16x8 kc2 = *(const bf16x8*)(kp + 32);
    bf16x8 kc3 = *(const bf16x8*)(kp + 48);
    bf16x8 vc0 = *(const bf16x8*)(vp);
    bf16x8 vc1 = *(const bf16x8*)(vp + 16);
    bf16x8 vc2 = *(const bf16x8*)(vq);
    bf16x8 vc3 = *(const bf16x8*)(vq + 16);

    f32x16 c = {};
    c = mfma32(kc0, qf0, c); c = mfma32(kc1, qf1, c);
    c = mfma32(kc2, qf2, c); c = mfma32(kc3, qf3, c);

    // K(1) prefetch (overwrites kc; old values already consumed by the MFMAs)
    kc0 = *(const bf16x8*)(kp + 32 * DM);
    kc1 = *(const bf16x8*)(kp + 32 * DM + 16);
    kc2 = *(const bf16x8*)(kp + 32 * DM + 32);
    kc3 = *(const bf16x8*)(kp + 32 * DM + 48);

    bf16x8 pa0, pa1;
    {
        const int sw = sbeg >> 6;
        const u64 w64 = cbv[sw] & mbv[sw];
        const uint32_t kw = ((uint32_t)(w64 >> (sbeg & 32))) >> (4 * hi);
        exppack(c, kw, lsum, pa0, pa1);
    }

    for (int t = 1; t < 32; ++t) {
        const int s0 = sbeg + 32 * t;
        // ---- V(t) issue (consumed NEXT iteration's PV)
        const bf16x8 vn0 = *(const bf16x8*)(vp + 32 * t);
        const bf16x8 vn1 = *(const bf16x8*)(vp + 32 * t + 16);
        const bf16x8 vn2 = *(const bf16x8*)(vq + 32 * t);
        const bf16x8 vn3 = *(const bf16x8*)(vq + 32 * t + 16);
        // ---- QK(t) with K(t) (resident since last iteration)
        f32x16 cn = {};
        cn = mfma32(kc0, qf0, cn); cn = mfma32(kc1, qf1, cn);
        cn = mfma32(kc2, qf2, cn); cn = mfma32(kc3, qf3, cn);
        // ---- K(t+1) issue (clamped at the end: harmless reload of tile 31)
        const int tn = (t < 31) ? t + 1 : 31;
        const bf16* kpn = kp + (size_t)32 * DM * tn;
        kc0 = *(const bf16x8*)(kpn);
        kc1 = *(const bf16x8*)(kpn + 16);
        kc2 = *(const bf16x8*)(kpn + 32);
        kc3 = *(const bf16x8*)(kpn + 48);
        // ---- PV(t-1): independent of QK(t) above -> fills the MFMA pipe
        accA = mfma32(pa0, vc0, accA);
        accA = mfma32(pa1, vc1, accA);
        accB = mfma32(pa0, vc2, accB);
        accB = mfma32(pa1, vc3, accB);
        // ---- exppack(t): QK latency absorbed by PV issue above
        const int sw = s0 >> 6;
        const u64 w64 = cbv[sw] & mbv[sw];
        const uint32_t kw = ((uint32_t)(w64 >> (s0 & 32))) >> (4 * hi);
        exppack(cn, kw, lsum, pa0, pa1);
        // ---- rotate V
        vc0 = vn0; vc1 = vn1; vc2 = vn2; vc3 = vn3;
    }
    // ---- epilogue: PV for tile 31
    accA = mfma32(pa0, vc0, accA);
    accA = mfma32(pa1, vc1, accA);
    accB = mfma32(pa0, vc2, accB);
    accB = mfma32(pa1, vc3, accB);

    // ---- merge the 4 S-chunk partials in LDS (once per kernel) ----
    MB[wave * 64 + hi * 32 + l31] = lsum;          // L[wave][hi*32 + q]
    float* accw = MB + 256 + wave * 2048;          // ACC[wave][q][d]
    #pragma unroll
    for (int reg = 0; reg < 16; ++reg) {
        const int q = (reg & 3) + 8 * (reg >> 2) + 4 * hi;
        accw[q * 64 + l31]      = accA[reg];
        accw[q * 64 + 32 + l31] = accB[reg];
    }
    __syncthreads();

    #pragma unroll
    for (int i = 0; i < 8; ++i) {
        const int idx = tid + i * 256;
        const int q = idx >> 6;
        const int d = idx & 63;
        const float o = MB[256 + q * 64 + d] + MB[256 + 2048 + q * 64 + d]
                      + MB[256 + 4096 + q * 64 + d] + MB[256 + 6144 + q * 64 + d];
        float tl = 0.f;
        #pragma unroll
        for (int wv = 0; wv < 4; ++wv) tl += MB[wv * 64 + q] + MB[wv * 64 + 32 + q];
        const float inv = tl > 0.f ? 1.f / tl : 0.f;
        AO[(size_t)(b * G_LEN + g0 + q) * DM + h * DK + d] = (bf16)(o * inv);
    }
}

// ---------------------------------------------------------------------------
// Row LayerNorm: one block per row (512 cols), 256 threads.
// ---------------------------------------------------------------------------
__global__ __launch_bounds__(256) void out_ln(
    const float* __restrict__ Y, const float* __restrict__ gam,
    const float* __restrict__ bet, float* __restrict__ out)
{
    const int row = blockIdx.x;
    const int tid = threadIdx.x;
    const float x0 = Y[(size_t)row * DM + tid];
    const float x1 = Y[(size_t)row * DM + 256 + tid];
    float s  = x0 + x1;
    float sq = x0 * x0 + x1 * x1;
    #pragma unroll
    for (int off = 1; off < 64; off <<= 1) {
        s  += __shfl_xor(s, off);
        sq += __shfl_xor(sq, off);
    }
    __shared__ float ss[4], ssq[4];
    const int wave = tid >> 6;
    if ((tid & 63) == 0) { ss[wave] = s; ssq[wave] = sq; }
    __syncthreads();
    s  = ss[0] + ss[1] + ss[2] + ss[3];
    sq = ssq[0] + ssq[1] + ssq[2] + ssq[3];
    const float mu  = s * (1.f / 512.f);
    const float var = sq * (1.f / 512.f) - mu * mu;
    const float rs  = rsqrtf(var + 1e-5f);
    out[(size_t)row * DM + tid]       = (x0 - mu) * rs * gam[tid] + bet[tid];
    out[(size_t)row * DM + 256 + tid] = (x1 - mu) * rs * gam[tid + 256] + bet[tid + 256];
}

// ---------------------------------------------------------------------------
extern "C" void kernel_launch(void* const* d_in, const int* in_sizes, int n_in,
                              void* d_out, int out_size, void* d_ws, size_t ws_size,
                              hipStream_t stream) {
    const float* queries     = (const float*)d_in[0];   // [4,1024,512]
    const float* keys_values = (const float*)d_in[1];   // [4,4096,512]
    const float* dq          = (const float*)d_in[2];   // [4,1,512]
    const float* dk          = (const float*)d_in[3];   // [4,1,512]
    const int*   mask        = (const int*)d_in[4];     // [4,4096]
    const void*  cis         = d_in[5];                 // [1024,4096] bool (dtype detected)
    const float* wq_w = (const float*)d_in[6];
    const float* wq_b = (const float*)d_in[7];
    const float* wk_w = (const float*)d_in[8];
    const float* wk_b = (const float*)d_in[9];
    const float* wv_w = (const float*)d_in[10];
    const float* wv_b = (const float*)d_in[11];
    const float* wo_w = (const float*)d_in[12];
    const float* wo_b = (const float*)d_in[13];
    const float* ln_g = (const float*)d_in[14];
    const float* ln_b = (const float*)d_in[15];
    float* out = (float*)d_out;

    char* ws = (char*)d_ws;
    bf16*  Qbf = (bf16*)(ws);                                   //  4 MB [4096,512] (pre-scaled x0.125)
    bf16*  Kbf = (bf16*)(ws + (4u << 20));                      // 16 MB [16384,512]
    bf16*  Vt  = (bf16*)(ws + (20u << 20));                     // 16 MB [4,8,64,4096]
    bf16*  AO  = (bf16*)(ws + (36u << 20));                     //  4 MB [4096,512]
    float* Yw  = (float*)(ws + (40u << 20));                    //  8 MB [4096,512]
    int*   cisflag = (int*)(ws + (48u << 20));                  //  4 B
    u64*   mbits   = (u64*)(ws + (48u << 20) + 4096);           //  2 KB [4][64]
    u64*   cbits   = (u64*)(ws + (48u << 20) + 8192);           // 512 KB [1024][64]

    detect_cis<<<1, 64, 0, stream>>>((const unsigned char*)cis, cisflag);
    pack_masks<<<(CIS_WORDS + BATCH * (S_LEN / 64) + 3) / 4, 256, 0, stream>>>(
        cis, mask, cisflag, cbits, mbits);

    // Q projection (pre-scaled by 1/sqrt(d_k)=0.125, exact pow2).
    gemm_proj<0, 0, 1024><<<dim3(64, 8), 256, 0, stream>>>(queries, wq_w, wq_b, dq, Qbf, 0.125f);
    // Fused K+V projections (shared A staging).
    gemm_kv<<<dim3(256, 8), 256, 0, stream>>>(keys_values, wk_w, wk_b, dk, wv_w, wv_b, Kbf, Vt);

    // Fused masked flash attention (32x32 MFMA, reg-only P, 2-stage pipeline)
    attn_kernel<<<dim3(32, 8, 4), 256, 0, stream>>>(Qbf, Kbf, Vt, mbits, cbits, AO);

    // Output projection (bf16 A) -> f32 scratch
    gemm_proj<1, 1, 1024><<<dim3(64, 8), 256, 0, stream>>>(AO, wo_w, wo_b, nullptr, Yw, 1.0f);

    // LayerNorm -> d_out
    out_ln<<<4096, 256, 0, stream>>>(Yw, ln_g, ln_b, out);
}

// Round 11
// 251.475 us; speedup vs baseline: 1.8673x; 1.1495x over previous
//
#include <hip/hip_runtime.h>
#include <stdint.h>
#include <stddef.h>

typedef __bf16 bf16;
typedef __bf16 bf16x4 __attribute__((ext_vector_type(4)));
typedef __bf16 bf16x8 __attribute__((ext_vector_type(8)));
typedef float f32x4 __attribute__((ext_vector_type(4)));
typedef float f32x16 __attribute__((ext_vector_type(16)));
typedef unsigned long long u64;

#define BATCH 4
#define G_LEN 1024
#define S_LEN 4096
#define DM 512
#define NH 8
#define DK 64
#define CIS_WORDS (G_LEN * (S_LEN / 64))   // 65536

__device__ __forceinline__ f32x4 mfma16(bf16x8 a, bf16x8 b, f32x4 c) {
    return __builtin_amdgcn_mfma_f32_16x16x32_bf16(a, b, c, 0, 0, 0);
}
__device__ __forceinline__ f32x16 mfma32(bf16x8 a, bf16x8 b, f32x16 c) {
    return __builtin_amdgcn_mfma_f32_32x32x16_bf16(a, b, c, 0, 0, 0);
}
// v_cvt_pk_bf16_f32: dst.lo = bf16(lo), dst.hi = bf16(hi). No builtin (m240).
__device__ __forceinline__ uint32_t cvtpk(float lo, float hi_) {
    uint32_t r;
    asm("v_cvt_pk_bf16_f32 %0, %1, %2" : "=v"(r) : "v"(lo), "v"(hi_));
    return r;
}
// v_permlane32_swap_b32: a.lanes[32:64] <-> b.lanes[0:32] (gfx950).
__device__ __forceinline__ void pswap(uint32_t& a, uint32_t& b) {
    asm("v_permlane32_swap_b32 %0, %1" : "+v"(a), "+v"(b));
}
__device__ __forceinline__ bf16x8 mk8(uint32_t a, uint32_t b, uint32_t c, uint32_t d) {
    union { uint32_t u[4]; bf16x8 v; } x;
    x.u[0] = a; x.u[1] = b; x.u[2] = c; x.u[3] = d;
    return x.v;
}
// masked exp + bf16 pack + permlane redistribute into PV A-fragments.
__device__ __forceinline__ void exppack(f32x16& c, uint32_t kw, float& lsum,
                                        bf16x8& pa0, bf16x8& pa1) {
    #pragma unroll
    for (int reg = 0; reg < 16; ++reg) {
        const int bit = (reg & 3) + 8 * (reg >> 2);
        const float e = __expf(c[reg]);
        c[reg] = ((kw >> bit) & 1u) ? e : 0.f;
    }
    lsum += ((c[0] + c[1]) + (c[2] + c[3])) + ((c[4] + c[5]) + (c[6] + c[7]))
          + ((c[8] + c[9]) + (c[10] + c[11])) + ((c[12] + c[13]) + (c[14] + c[15]));
    uint32_t wa0 = cvtpk(c[0],  c[1]),  wa1 = cvtpk(c[2],  c[3]);
    uint32_t wb0 = cvtpk(c[4],  c[5]),  wb1 = cvtpk(c[6],  c[7]);
    uint32_t wc0 = cvtpk(c[8],  c[9]),  wc1 = cvtpk(c[10], c[11]);
    uint32_t wd0 = cvtpk(c[12], c[13]), wd1 = cvtpk(c[14], c[15]);
    pswap(wa0, wb0); pswap(wa1, wb1); pswap(wc0, wd0); pswap(wc1, wd1);
    pa0 = mk8(wa0, wa1, wb0, wb1);   // s = 8hi + 0..7
    pa1 = mk8(wc0, wc1, wd0, wd1);   // s = 16 + 8hi + 0..7
}
// async global->LDS, 16B/lane. LDS dest is WAVE-UNIFORM base (HW adds lane*16).
__device__ __forceinline__ void stage16(const bf16* g, char* l) {
    __builtin_amdgcn_global_load_lds(
        (const __attribute__((address_space(1))) void*)g,
        (__attribute__((address_space(3))) void*)l, 16, 0, 0);
}

// ---------------------------------------------------------------------------
// cis dtype detection (bool vs int32) — see round 1 notes. flag=1 -> bytes.
// ---------------------------------------------------------------------------
__global__ void detect_cis(const unsigned char* __restrict__ cis, int* __restrict__ flag) {
    int any = 0;
    for (int i = threadIdx.x; i < 16384; i += 64)
        any |= cis[4 * i + 1];
    #pragma unroll
    for (int off = 1; off < 64; off <<= 1) any |= __shfl_xor(any, off);
    if (threadIdx.x == 0) flag[0] = (any != 0) ? 1 : 0;
}

// ---------------------------------------------------------------------------
// Pack cis[g][s] and mask[b][s] into bit-words (one wave per u64 via ballot).
// ---------------------------------------------------------------------------
__global__ __launch_bounds__(256) void pack_masks(
    const void* __restrict__ cisv, const int* __restrict__ mask,
    const int* __restrict__ flag, u64* __restrict__ cbits, u64* __restrict__ mbits)
{
    const int wid  = blockIdx.x * 4 + (threadIdx.x >> 6);
    const int lane = threadIdx.x & 63;
    if (wid < CIS_WORDS) {
        int v;
        if (flag[0]) v = ((const unsigned char*)cisv)[(size_t)wid * 64 + lane];
        else         v = ((const int*)cisv)[(size_t)wid * 64 + lane];
        const u64 bits = __ballot(v != 0);
        if (lane == 0) cbits[wid] = bits;
    } else if (wid < CIS_WORDS + BATCH * (S_LEN / 64)) {
        const int w2 = wid - CIS_WORDS;               // b*64 + sw
        const u64 bits = __ballot(mask[w2 * 64 + lane] != 0);
        if (lane == 0) mbits[w2] = bits;
    }
}

// ---------------------------------------------------------------------------
// GEMM: Y[m][n] = (sum_k X[m][k]*W[n][k] + bias[n] (+ shift)) * oscale
// ---------------------------------------------------------------------------
template<int A_IS_BF16, int OUT_F32, int ROWS_PER_B>
__global__ __launch_bounds__(256) void gemm_proj(
    const void* __restrict__ Ap, const float* __restrict__ W,
    const float* __restrict__ bias, const float* __restrict__ shift,
    void* __restrict__ Out, float oscale)
{
    __shared__ bf16 As[64][72];
    __shared__ bf16 Bs[64][72];
    const int tid  = threadIdx.x;
    const int lane = tid & 63;
    const int wave = tid >> 6;
    const int l15  = lane & 15;
    const int l4   = lane >> 4;
    const int m0   = blockIdx.x * 64;
    const int n0   = blockIdx.y * 64;

    f32x4 acc[4] = {};

    for (int kt = 0; kt < DM; kt += 64) {
        #pragma unroll
        for (int i = 0; i < 4; ++i) {
            const int q   = tid + i * 256;
            const int row = q >> 4;
            const int kq  = (q & 15) * 4;
            bf16x4 av;
            if (A_IS_BF16) {
                av = *(const bf16x4*)((const bf16*)Ap + (size_t)(m0 + row) * DM + kt + kq);
            } else {
                const float4 v = *(const float4*)((const float*)Ap + (size_t)(m0 + row) * DM + kt + kq);
                av[0] = (bf16)v.x; av[1] = (bf16)v.y; av[2] = (bf16)v.z; av[3] = (bf16)v.w;
            }
            *(bf16x4*)&As[row][kq] = av;
            const float4 w = *(const float4*)(W + (size_t)(n0 + row) * DM + kt + kq);
            bf16x4 bv;
            bv[0] = (bf16)w.x; bv[1] = (bf16)w.y; bv[2] = (bf16)w.z; bv[3] = (bf16)w.w;
            *(bf16x4*)&Bs[row][kq] = bv;
        }
        __syncthreads();
        #pragma unroll
        for (int ks = 0; ks < 64; ks += 32) {
            const bf16x8 a = *(const bf16x8*)&As[wave * 16 + l15][ks + 8 * l4];
            #pragma unroll
            for (int n = 0; n < 4; ++n) {
                const bf16x8 b = *(const bf16x8*)&Bs[n * 16 + l15][ks + 8 * l4];
                acc[n] = mfma16(a, b, acc[n]);
            }
        }
        __syncthreads();
    }

    #pragma unroll
    for (int n = 0; n < 4; ++n) {
        const int col = n0 + n * 16 + l15;
        const float bv = bias[col];
        #pragma unroll
        for (int r = 0; r < 4; ++r) {
            const int m = m0 + wave * 16 + l4 * 4 + r;
            float v = acc[n][r] + bv;
            if (shift) v += shift[(m / ROWS_PER_B) * DM + col];
            v *= oscale;
            if (OUT_F32) ((float*)Out)[(size_t)m * DM + col] = v;
            else         ((bf16*)Out)[(size_t)m * DM + col] = (bf16)v;
        }
    }
}

// ---------------------------------------------------------------------------
// Fused K+V projection (shared A staging). K -> [m][col] (+dk); V -> Vt[b][col][s].
// ---------------------------------------------------------------------------
__global__ __launch_bounds__(256) void gemm_kv(
    const float* __restrict__ X, const float* __restrict__ Wk,
    const float* __restrict__ bk, const float* __restrict__ dkv,
    const float* __restrict__ Wv, const float* __restrict__ bv,
    bf16* __restrict__ OutK, bf16* __restrict__ OutVt)
{
    __shared__ bf16 As[64][72];
    __shared__ bf16 Bk[64][72];
    __shared__ bf16 Bv[64][72];
    const int tid  = threadIdx.x;
    const int lane = tid & 63;
    const int wave = tid >> 6;
    const int l15  = lane & 15;
    const int l4   = lane >> 4;
    const int m0   = blockIdx.x * 64;
    const int n0   = blockIdx.y * 64;

    f32x4 ak[4] = {}, av[4] = {};

    for (int kt = 0; kt < DM; kt += 64) {
        #pragma unroll
        for (int i = 0; i < 4; ++i) {
            const int q   = tid + i * 256;
            const int row = q >> 4;
            const int kq  = (q & 15) * 4;
            const float4 x = *(const float4*)(X  + (size_t)(m0 + row) * DM + kt + kq);
            const float4 k = *(const float4*)(Wk + (size_t)(n0 + row) * DM + kt + kq);
            const float4 v = *(const float4*)(Wv + (size_t)(n0 + row) * DM + kt + kq);
            bf16x4 xa, ka, va;
            xa[0] = (bf16)x.x; xa[1] = (bf16)x.y; xa[2] = (bf16)x.z; xa[3] = (bf16)x.w;
            ka[0] = (bf16)k.x; ka[1] = (bf16)k.y; ka[2] = (bf16)k.z; ka[3] = (bf16)k.w;
            va[0] = (bf16)v.x; va[1] = (bf16)v.y; va[2] = (bf16)v.z; va[3] = (bf16)v.w;
            *(bf16x4*)&As[row][kq] = xa;
            *(bf16x4*)&Bk[row][kq] = ka;
            *(bf16x4*)&Bv[row][kq] = va;
        }
        __syncthreads();
        #pragma unroll
        for (int ks = 0; ks < 64; ks += 32) {
            const bf16x8 a = *(const bf16x8*)&As[wave * 16 + l15][ks + 8 * l4];
            #pragma unroll
            for (int n = 0; n < 4; ++n) {
                const bf16x8 bkf = *(const bf16x8*)&Bk[n * 16 + l15][ks + 8 * l4];
                const bf16x8 bvf = *(const bf16x8*)&Bv[n * 16 + l15][ks + 8 * l4];
                ak[n] = mfma16(a, bkf, ak[n]);
                av[n] = mfma16(a, bvf, av[n]);
            }
        }
        __syncthreads();
    }

    #pragma unroll
    for (int n = 0; n < 4; ++n) {
        const int col = n0 + n * 16 + l15;
        const float bkc = bk[col];
        const float bvc = bv[col];
        #pragma unroll
        for (int r = 0; r < 4; ++r) {
            const int m  = m0 + wave * 16 + l4 * 4 + r;
            const int bb = m >> 12;                 // batch = m / 4096
            OutK[(size_t)m * DM + col] = (bf16)(ak[n][r] + bkc + dkv[bb * DM + col]);
            OutVt[((size_t)bb * DM + col) * 4096 + (m & 4095)] = (bf16)(av[n][r] + bvc);
        }
    }
}

// ---------------------------------------------------------------------------
// Flash attention v2: LDS-shared K/V (4x reuse), no S-split, no merge.
// Block = 4 waves x 32 q-rows = 128 q; grid 256 (1 block/CU, XCD-colocated).
// Per 64-s tile: K 8KB + V 8KB staged via global_load_lds (16B), triple-
// buffered 2-ahead, counted vmcnt(8) + raw s_barrier (never drain in loop).
// LDS XOR swizzle col16 ^= row&7 (source-side + read-side, rule 21) cuts
// the 32-way row-major conflict to 4-way. P path stays register-only.
// Round-10 model: 1.07GB @7.2TB/s from L2/L3 was the wall; now 256MB.
// ---------------------------------------------------------------------------
__global__ __launch_bounds__(256, 1) void attn_kernel(
    const bf16* __restrict__ Qb, const bf16* __restrict__ Kb,
    const bf16* __restrict__ Vt, const u64* __restrict__ mbits,
    const u64* __restrict__ cbits, bf16* __restrict__ AO)
{
    __shared__ __align__(16) char sm[49152];   // 3 x (8KB K | 8KB V); epilogue overlays

    const int tid  = threadIdx.x;
    const int lane = tid & 63;
    const int wave = tid >> 6;
    const int l31  = lane & 31;
    const int hi   = lane >> 5;

    // 256 blocks = 8 XCD x 4 pairs x 8 g-tiles(128q). Same pair -> same XCD.
    const int flat = blockIdx.x;
    const int xcd  = flat & 7;
    const int slot = flat >> 3;               // 0..31
    const int pr   = xcd * 4 + (slot >> 3);   // (b,h) pair 0..31
    const int b    = pr >> 3;
    const int h    = pr & 7;
    const int g0   = (slot & 7) * 128;

    // Q B-frags: q = g0 + wave*32 + l31, dk = 16m + 8hi + j (Q pre-scaled 0.125)
    const bf16* qbase = Qb + (size_t)(b * G_LEN + g0 + wave * 32 + l31) * DM + h * DK + 8 * hi;
    const bf16x8 qf0 = *(const bf16x8*)(qbase);
    const bf16x8 qf1 = *(const bf16x8*)(qbase + 16);
    const bf16x8 qf2 = *(const bf16x8*)(qbase + 32);
    const bf16x8 qf3 = *(const bf16x8*)(qbase + 48);

    const bf16* Kh = Kb + (size_t)b * S_LEN * DM + h * DK;
    const bf16* Vh = Vt + (size_t)(b * NH + h) * DK * S_LEN;
    const u64*  mbv = mbits + b * (S_LEN / 64);
    const u64*  cbv = cbits + (size_t)(g0 + wave * 32 + l31) * (S_LEN / 64);

    // Staging descriptors: waves 0,1 stage K tile rows, waves 2,3 stage V rows.
    // Thread's element: lds byte off = wave*4096 + i*1024 + lane*16 ->
    // row = (wave&1)*32 + i*8 + (lane>>3), col16 = lane&7 (same for all i).
    // Source pre-swizzle: col16s = col16 ^ (row&7) = (lane&7)^(rowbase&7).
    const bool isK    = (wave < 2);
    const int rowbase = (wave & 1) * 32 + (lane >> 3);
    const int col16s  = (lane & 7) ^ (rowbase & 7);
    const int swz     = l31 & 7;   // read-side swizzle key

#define STAGE(tt, bufi) do {                                                   \
    char* ldw = sm + (bufi) * 16384 + wave * 4096;                             \
    _Pragma("unroll")                                                          \
    for (int i = 0; i < 4; ++i) {                                              \
        const int row = rowbase + i * 8;                                       \
        const bf16* g = isK                                                    \
            ? (Kh + (size_t)((tt) * 64 + row) * DM + col16s * 8)               \
            : (Vh + (size_t)row * S_LEN + (tt) * 64 + col16s * 8);             \
        stage16(g, ldw + i * 1024);                                            \
    }                                                                          \
} while (0)

    f32x16 accA = {};   // d = l31
    f32x16 accB = {};   // d = 32 + l31
    float lsum = 0.f;

    // prologue: tiles 0,1 in flight (8 loads/thread outstanding)
    STAGE(0, 0);
    STAGE(1, 1);

    for (int t = 0; t < 64; ++t) {
        __builtin_amdgcn_s_barrier();              // A: buf[(t+2)%3] free to overwrite
        __builtin_amdgcn_sched_barrier(0);
        if (t + 2 < 64) STAGE(t + 2, (t + 2) % 3);
        if (t < 62)       asm volatile("s_waitcnt vmcnt(8)" ::: "memory");
        else if (t == 62) asm volatile("s_waitcnt vmcnt(4)" ::: "memory");
        else              asm volatile("s_waitcnt vmcnt(0)" ::: "memory");
        __builtin_amdgcn_s_barrier();              // B: buf[t%3] staged for all waves
        __builtin_amdgcn_sched_barrier(0);

        const char* bK = sm + (t % 3) * 16384;
        const char* bV = bK + 8192;

        // ---- QK^T (A = K from LDS, swizzled read): D[s_sub][q]
#define KF(ss, m) (*(const bf16x8*)(bK + ((ss) * 32 + l31) * 128 + (((2 * (m) + hi) ^ swz) * 16)))
        f32x16 c0 = {}, c1 = {};
        c0 = mfma32(KF(0, 0), qf0, c0); c0 = mfma32(KF(0, 1), qf1, c0);
        c0 = mfma32(KF(0, 2), qf2, c0); c0 = mfma32(KF(0, 3), qf3, c0);
        c1 = mfma32(KF(1, 0), qf0, c1); c1 = mfma32(KF(1, 1), qf1, c1);
        c1 = mfma32(KF(1, 2), qf2, c1); c1 = mfma32(KF(1, 3), qf3, c1);

        // ---- masks: one u64 covers the 64-s tile; subtile 0 = bits 0..31
        const u64 w64 = cbv[t] & mbv[t];
        const uint32_t kw0 = ((uint32_t)w64) >> (4 * hi);
        const uint32_t kw1 = ((uint32_t)(w64 >> 32)) >> (4 * hi);

        bf16x8 pa0, pa1, pb0, pb1;
        exppack(c0, kw0, lsum, pa0, pa1);
        exppack(c1, kw1, lsum, pb0, pb1);

        // ---- PV (B = V from LDS, swizzled read): acc[q][d]
#define VF(ss, ks, dh) (*(const bf16x8*)(bV + ((dh) * 32 + l31) * 128 + ((((ss) * 4 + (ks) * 2 + hi) ^ swz) * 16)))
        accA = mfma32(pa0, VF(0, 0, 0), accA); accA = mfma32(pa1, VF(0, 1, 0), accA);
        accA = mfma32(pb0, VF(1, 0, 0), accA); accA = mfma32(pb1, VF(1, 1, 0), accA);
        accB = mfma32(pa0, VF(0, 0, 1), accB); accB = mfma32(pa1, VF(0, 1, 1), accB);
        accB = mfma32(pb0, VF(1, 0, 1), accB); accB = mfma32(pb1, VF(1, 1, 1), accB);
    }
#undef KF
#undef VF
#undef STAGE

    // ---- epilogue: denominators (merge hi-halves) + normalize + write ----
    const float tl = lsum + __shfl_xor(lsum, 32);   // lane q holds full denom
    __syncthreads();                                 // all compute done; reuse sm
    float* MB = (float*)sm;                          // L[128] | ACC[128][64]
    if (hi == 0) MB[wave * 32 + l31] = tl;
    float* aw = MB + 128 + (wave * 32) * 64;
    #pragma unroll
    for (int reg = 0; reg < 16; ++reg) {
        const int q = (reg & 3) + 8 * (reg >> 2) + 4 * hi;
        aw[q * 64 + l31]      = accA[reg];
        aw[q * 64 + 32 + l31] = accB[reg];
    }
    __syncthreads();

    #pragma unroll
    for (int i = 0; i < 32; ++i) {
        const int idx = tid + i * 256;
        const int q = idx >> 6;
        const int d = idx & 63;
        const float wl = MB[q];
        const float inv = wl > 0.f ? 1.f / wl : 0.f;
        AO[(size_t)(b * G_LEN + g0 + q) * DM + h * DK + d] = (bf16)(MB[128 + q * 64 + d] * inv);
    }
}

// ---------------------------------------------------------------------------
// Row LayerNorm: one block per row (512 cols), 256 threads.
// ---------------------------------------------------------------------------
__global__ __launch_bounds__(256) void out_ln(
    const float* __restrict__ Y, const float* __restrict__ gam,
    const float* __restrict__ bet, float* __restrict__ out)
{
    const int row = blockIdx.x;
    const int tid = threadIdx.x;
    const float x0 = Y[(size_t)row * DM + tid];
    const float x1 = Y[(size_t)row * DM + 256 + tid];
    float s  = x0 + x1;
    float sq = x0 * x0 + x1 * x1;
    #pragma unroll
    for (int off = 1; off < 64; off <<= 1) {
        s  += __shfl_xor(s, off);
        sq += __shfl_xor(sq, off);
    }
    __shared__ float ss[4], ssq[4];
    const int wave = tid >> 6;
    if ((tid & 63) == 0) { ss[wave] = s; ssq[wave] = sq; }
    __syncthreads();
    s  = ss[0] + ss[1] + ss[2] + ss[3];
    sq = ssq[0] + ssq[1] + ssq[2] + ssq[3];
    const float mu  = s * (1.f / 512.f);
    const float var = sq * (1.f / 512.f) - mu * mu;
    const float rs  = rsqrtf(var + 1e-5f);
    out[(size_t)row * DM + tid]       = (x0 - mu) * rs * gam[tid] + bet[tid];
    out[(size_t)row * DM + 256 + tid] = (x1 - mu) * rs * gam[tid + 256] + bet[tid + 256];
}

// ---------------------------------------------------------------------------
extern "C" void kernel_launch(void* const* d_in, const int* in_sizes, int n_in,
                              void* d_out, int out_size, void* d_ws, size_t ws_size,
                              hipStream_t stream) {
    const float* queries     = (const float*)d_in[0];   // [4,1024,512]
    const float* keys_values = (const float*)d_in[1];   // [4,4096,512]
    const float* dq          = (const float*)d_in[2];   // [4,1,512]
    const float* dk          = (const float*)d_in[3];   // [4,1,512]
    const int*   mask        = (const int*)d_in[4];     // [4,4096]
    const void*  cis         = d_in[5];                 // [1024,4096] bool (dtype detected)
    const float* wq_w = (const float*)d_in[6];
    const float* wq_b = (const float*)d_in[7];
    const float* wk_w = (const float*)d_in[8];
    const float* wk_b = (const float*)d_in[9];
    const float* wv_w = (const float*)d_in[10];
    const float* wv_b = (const float*)d_in[11];
    const float* wo_w = (const float*)d_in[12];
    const float* wo_b = (const float*)d_in[13];
    const float* ln_g = (const float*)d_in[14];
    const float* ln_b = (const float*)d_in[15];
    float* out = (float*)d_out;

    char* ws = (char*)d_ws;
    bf16*  Qbf = (bf16*)(ws);                                   //  4 MB [4096,512] (pre-scaled x0.125)
    bf16*  Kbf = (bf16*)(ws + (4u << 20));                      // 16 MB [16384,512]
    bf16*  Vt  = (bf16*)(ws + (20u << 20));                     // 16 MB [4,8,64,4096]
    bf16*  AO  = (bf16*)(ws + (36u << 20));                     //  4 MB [4096,512]
    float* Yw  = (float*)(ws + (40u << 20));                    //  8 MB [4096,512]
    int*   cisflag = (int*)(ws + (48u << 20));                  //  4 B
    u64*   mbits   = (u64*)(ws + (48u << 20) + 4096);           //  2 KB [4][64]
    u64*   cbits   = (u64*)(ws + (48u << 20) + 8192);           // 512 KB [1024][64]

    detect_cis<<<1, 64, 0, stream>>>((const unsigned char*)cis, cisflag);
    pack_masks<<<(CIS_WORDS + BATCH * (S_LEN / 64) + 3) / 4, 256, 0, stream>>>(
        cis, mask, cisflag, cbits, mbits);

    // Q projection (pre-scaled by 1/sqrt(d_k)=0.125, exact pow2).
    gemm_proj<0, 0, 1024><<<dim3(64, 8), 256, 0, stream>>>(queries, wq_w, wq_b, dq, Qbf, 0.125f);
    // Fused K+V projections (shared A staging).
    gemm_kv<<<dim3(256, 8), 256, 0, stream>>>(keys_values, wk_w, wk_b, dk, wv_w, wv_b, Kbf, Vt);

    // Fused masked flash attention (LDS-shared K/V, async staged, no merge)
    attn_kernel<<<256, 256, 0, stream>>>(Qbf, Kbf, Vt, mbits, cbits, AO);

    // Output projection (bf16 A) -> f32 scratch
    gemm_proj<1, 1, 1024><<<dim3(64, 8), 256, 0, stream>>>(AO, wo_w, wo_b, nullptr, Yw, 1.0f);

    // LayerNorm -> d_out
    out_ln<<<4096, 256, 0, stream>>>(Yw, ln_g, ln_b, out);
}

// Round 12
// 228.802 us; speedup vs baseline: 2.0523x; 1.0991x over previous
//
#include <hip/hip_runtime.h>
#include <stdint.h>
#include <stddef.h>

typedef __bf16 bf16;
typedef __bf16 bf16x4 __attribute__((ext_vector_type(4)));
typedef __bf16 bf16x8 __attribute__((ext_vector_type(8)));
typedef float f32x4 __attribute__((ext_vector_type(4)));
typedef float f32x16 __attribute__((ext_vector_type(16)));
typedef unsigned long long u64;

#define BATCH 4
#define G_LEN 1024
#define S_LEN 4096
#define DM 512
#define NH 8
#define DK 64
#define CIS_WORDS (G_LEN * (S_LEN / 64))   // 65536

__device__ __forceinline__ f32x4 mfma16(bf16x8 a, bf16x8 b, f32x4 c) {
    return __builtin_amdgcn_mfma_f32_16x16x32_bf16(a, b, c, 0, 0, 0);
}
__device__ __forceinline__ f32x16 mfma32(bf16x8 a, bf16x8 b, f32x16 c) {
    return __builtin_amdgcn_mfma_f32_32x32x16_bf16(a, b, c, 0, 0, 0);
}
// v_cvt_pk_bf16_f32: dst.lo = bf16(lo), dst.hi = bf16(hi). No builtin (m240).
__device__ __forceinline__ uint32_t cvtpk(float lo, float hi_) {
    uint32_t r;
    asm("v_cvt_pk_bf16_f32 %0, %1, %2" : "=v"(r) : "v"(lo), "v"(hi_));
    return r;
}
// v_permlane32_swap_b32: a.lanes[32:64] <-> b.lanes[0:32] (gfx950).
__device__ __forceinline__ void pswap(uint32_t& a, uint32_t& b) {
    asm("v_permlane32_swap_b32 %0, %1" : "+v"(a), "+v"(b));
}
__device__ __forceinline__ bf16x8 mk8(uint32_t a, uint32_t b, uint32_t c, uint32_t d) {
    union { uint32_t u[4]; bf16x8 v; } x;
    x.u[0] = a; x.u[1] = b; x.u[2] = c; x.u[3] = d;
    return x.v;
}
// masked exp + bf16 pack + permlane redistribute into PV A-fragments.
__device__ __forceinline__ void exppack(f32x16& c, uint32_t kw, float& lsum,
                                        bf16x8& pa0, bf16x8& pa1) {
    #pragma unroll
    for (int reg = 0; reg < 16; ++reg) {
        const int bit = (reg & 3) + 8 * (reg >> 2);
        const float e = __expf(c[reg]);
        c[reg] = ((kw >> bit) & 1u) ? e : 0.f;
    }
    lsum += ((c[0] + c[1]) + (c[2] + c[3])) + ((c[4] + c[5]) + (c[6] + c[7]))
          + ((c[8] + c[9]) + (c[10] + c[11])) + ((c[12] + c[13]) + (c[14] + c[15]));
    uint32_t wa0 = cvtpk(c[0],  c[1]),  wa1 = cvtpk(c[2],  c[3]);
    uint32_t wb0 = cvtpk(c[4],  c[5]),  wb1 = cvtpk(c[6],  c[7]);
    uint32_t wc0 = cvtpk(c[8],  c[9]),  wc1 = cvtpk(c[10], c[11]);
    uint32_t wd0 = cvtpk(c[12], c[13]), wd1 = cvtpk(c[14], c[15]);
    pswap(wa0, wb0); pswap(wa1, wb1); pswap(wc0, wd0); pswap(wc1, wd1);
    pa0 = mk8(wa0, wa1, wb0, wb1);   // s = 8hi + 0..7
    pa1 = mk8(wc0, wc1, wd0, wd1);   // s = 16 + 8hi + 0..7
}
// async global->LDS, 16B/lane. LDS dest is WAVE-UNIFORM base (HW adds lane*16).
__device__ __forceinline__ void stage16(const bf16* g, char* l) {
    __builtin_amdgcn_global_load_lds(
        (const __attribute__((address_space(1))) void*)g,
        (__attribute__((address_space(3))) void*)l, 16, 0, 0);
}

// ---------------------------------------------------------------------------
// cis dtype detection (bool vs int32) — see round 1 notes. flag=1 -> bytes.
// ---------------------------------------------------------------------------
__global__ void detect_cis(const unsigned char* __restrict__ cis, int* __restrict__ flag) {
    int any = 0;
    for (int i = threadIdx.x; i < 16384; i += 64)
        any |= cis[4 * i + 1];
    #pragma unroll
    for (int off = 1; off < 64; off <<= 1) any |= __shfl_xor(any, off);
    if (threadIdx.x == 0) flag[0] = (any != 0) ? 1 : 0;
}

// ---------------------------------------------------------------------------
// Pack cis[g][s] and mask[b][s] into bit-words (one wave per u64 via ballot).
// ---------------------------------------------------------------------------
__global__ __launch_bounds__(256) void pack_masks(
    const void* __restrict__ cisv, const int* __restrict__ mask,
    const int* __restrict__ flag, u64* __restrict__ cbits, u64* __restrict__ mbits)
{
    const int wid  = blockIdx.x * 4 + (threadIdx.x >> 6);
    const int lane = threadIdx.x & 63;
    if (wid < CIS_WORDS) {
        int v;
        if (flag[0]) v = ((const unsigned char*)cisv)[(size_t)wid * 64 + lane];
        else         v = ((const int*)cisv)[(size_t)wid * 64 + lane];
        const u64 bits = __ballot(v != 0);
        if (lane == 0) cbits[wid] = bits;
    } else if (wid < CIS_WORDS + BATCH * (S_LEN / 64)) {
        const int w2 = wid - CIS_WORDS;               // b*64 + sw
        const u64 bits = __ballot(mask[w2 * 64 + lane] != 0);
        if (lane == 0) mbits[w2] = bits;
    }
}

// ---------------------------------------------------------------------------
// GEMM: Y[m][n] = (sum_k X[m][k]*W[n][k] + bias[n] (+ shift)) * oscale
// ---------------------------------------------------------------------------
template<int A_IS_BF16, int OUT_F32, int ROWS_PER_B>
__global__ __launch_bounds__(256) void gemm_proj(
    const void* __restrict__ Ap, const float* __restrict__ W,
    const float* __restrict__ bias, const float* __restrict__ shift,
    void* __restrict__ Out, float oscale)
{
    __shared__ bf16 As[64][72];
    __shared__ bf16 Bs[64][72];
    const int tid  = threadIdx.x;
    const int lane = tid & 63;
    const int wave = tid >> 6;
    const int l15  = lane & 15;
    const int l4   = lane >> 4;
    const int m0   = blockIdx.x * 64;
    const int n0   = blockIdx.y * 64;

    f32x4 acc[4] = {};

    for (int kt = 0; kt < DM; kt += 64) {
        #pragma unroll
        for (int i = 0; i < 4; ++i) {
            const int q   = tid + i * 256;
            const int row = q >> 4;
            const int kq  = (q & 15) * 4;
            bf16x4 av;
            if (A_IS_BF16) {
                av = *(const bf16x4*)((const bf16*)Ap + (size_t)(m0 + row) * DM + kt + kq);
            } else {
                const float4 v = *(const float4*)((const float*)Ap + (size_t)(m0 + row) * DM + kt + kq);
                av[0] = (bf16)v.x; av[1] = (bf16)v.y; av[2] = (bf16)v.z; av[3] = (bf16)v.w;
            }
            *(bf16x4*)&As[row][kq] = av;
            const float4 w = *(const float4*)(W + (size_t)(n0 + row) * DM + kt + kq);
            bf16x4 bv;
            bv[0] = (bf16)w.x; bv[1] = (bf16)w.y; bv[2] = (bf16)w.z; bv[3] = (bf16)w.w;
            *(bf16x4*)&Bs[row][kq] = bv;
        }
        __syncthreads();
        #pragma unroll
        for (int ks = 0; ks < 64; ks += 32) {
            const bf16x8 a = *(const bf16x8*)&As[wave * 16 + l15][ks + 8 * l4];
            #pragma unroll
            for (int n = 0; n < 4; ++n) {
                const bf16x8 b = *(const bf16x8*)&Bs[n * 16 + l15][ks + 8 * l4];
                acc[n] = mfma16(a, b, acc[n]);
            }
        }
        __syncthreads();
    }

    #pragma unroll
    for (int n = 0; n < 4; ++n) {
        const int col = n0 + n * 16 + l15;
        const float bv = bias[col];
        #pragma unroll
        for (int r = 0; r < 4; ++r) {
            const int m = m0 + wave * 16 + l4 * 4 + r;
            float v = acc[n][r] + bv;
            if (shift) v += shift[(m / ROWS_PER_B) * DM + col];
            v *= oscale;
            if (OUT_F32) ((float*)Out)[(size_t)m * DM + col] = v;
            else         ((bf16*)Out)[(size_t)m * DM + col] = (bf16)v;
        }
    }
}

// ---------------------------------------------------------------------------
// Fused K+V projection (shared A staging). K -> [m][col] (+dk); V -> Vt[b][col][s].
// ---------------------------------------------------------------------------
__global__ __launch_bounds__(256) void gemm_kv(
    const float* __restrict__ X, const float* __restrict__ Wk,
    const float* __restrict__ bk, const float* __restrict__ dkv,
    const float* __restrict__ Wv, const float* __restrict__ bv,
    bf16* __restrict__ OutK, bf16* __restrict__ OutVt)
{
    __shared__ bf16 As[64][72];
    __shared__ bf16 Bk[64][72];
    __shared__ bf16 Bv[64][72];
    const int tid  = threadIdx.x;
    const int lane = tid & 63;
    const int wave = tid >> 6;
    const int l15  = lane & 15;
    const int l4   = lane >> 4;
    const int m0   = blockIdx.x * 64;
    const int n0   = blockIdx.y * 64;

    f32x4 ak[4] = {}, av[4] = {};

    for (int kt = 0; kt < DM; kt += 64) {
        #pragma unroll
        for (int i = 0; i < 4; ++i) {
            const int q   = tid + i * 256;
            const int row = q >> 4;
            const int kq  = (q & 15) * 4;
            const float4 x = *(const float4*)(X  + (size_t)(m0 + row) * DM + kt + kq);
            const float4 k = *(const float4*)(Wk + (size_t)(n0 + row) * DM + kt + kq);
            const float4 v = *(const float4*)(Wv + (size_t)(n0 + row) * DM + kt + kq);
            bf16x4 xa, ka, va;
            xa[0] = (bf16)x.x; xa[1] = (bf16)x.y; xa[2] = (bf16)x.z; xa[3] = (bf16)x.w;
            ka[0] = (bf16)k.x; ka[1] = (bf16)k.y; ka[2] = (bf16)k.z; ka[3] = (bf16)k.w;
            va[0] = (bf16)v.x; va[1] = (bf16)v.y; va[2] = (bf16)v.z; va[3] = (bf16)v.w;
            *(bf16x4*)&As[row][kq] = xa;
            *(bf16x4*)&Bk[row][kq] = ka;
            *(bf16x4*)&Bv[row][kq] = va;
        }
        __syncthreads();
        #pragma unroll
        for (int ks = 0; ks < 64; ks += 32) {
            const bf16x8 a = *(const bf16x8*)&As[wave * 16 + l15][ks + 8 * l4];
            #pragma unroll
            for (int n = 0; n < 4; ++n) {
                const bf16x8 bkf = *(const bf16x8*)&Bk[n * 16 + l15][ks + 8 * l4];
                const bf16x8 bvf = *(const bf16x8*)&Bv[n * 16 + l15][ks + 8 * l4];
                ak[n] = mfma16(a, bkf, ak[n]);
                av[n] = mfma16(a, bvf, av[n]);
            }
        }
        __syncthreads();
    }

    #pragma unroll
    for (int n = 0; n < 4; ++n) {
        const int col = n0 + n * 16 + l15;
        const float bkc = bk[col];
        const float bvc = bv[col];
        #pragma unroll
        for (int r = 0; r < 4; ++r) {
            const int m  = m0 + wave * 16 + l4 * 4 + r;
            const int bb = m >> 12;                 // batch = m / 4096
            OutK[(size_t)m * DM + col] = (bf16)(ak[n][r] + bkc + dkv[bb * DM + col]);
            OutVt[((size_t)bb * DM + col) * 4096 + (m & 4095)] = (bf16)(av[n][r] + bvc);
        }
    }
}

// ---------------------------------------------------------------------------
// Flash attention v3: LDS-shared K/V + 2-way S-split for occupancy.
// Round-11 audit: no-split = exactly 1 wave/SIMD chip-wide (1024 waves) ->
// all chain latency exposed (VALUBusy 36%, MfmaUtil 11%, Occ 11.5%).
// Grid 512 = 8 XCD x 4 pairs x 8 g-tiles x 2 S-halves; 2 blocks/CU,
// 2 waves/SIMD. Each block: 128 q-rows x 2048 s; partial (numerator bf16,
// denominator f32) written to scratch; tiny merge kernel normalizes -> AO.
// Staging/barrier/vmcnt discipline unchanged (3-buf, 2-ahead, vmcnt(8)).
// ---------------------------------------------------------------------------
__global__ __launch_bounds__(256, 1) void attn_kernel(
    const bf16* __restrict__ Qb, const bf16* __restrict__ Kb,
    const bf16* __restrict__ Vt, const u64* __restrict__ mbits,
    const u64* __restrict__ cbits, bf16* __restrict__ PO, float* __restrict__ PL)
{
    __shared__ __align__(16) char sm[49152];   // 3 x (8KB K | 8KB V)

    const int tid  = threadIdx.x;
    const int lane = tid & 63;
    const int wave = tid >> 6;
    const int l31  = lane & 31;
    const int hi   = lane >> 5;

    // 512 blocks = 8 XCD x 4 pairs x (8 g-tiles x 2 S-halves).
    const int flat = blockIdx.x;
    const int xcd  = flat & 7;
    const int slot = flat >> 3;               // 0..63
    const int pr   = xcd * 4 + (slot >> 4);   // (b,h) pair 0..31
    const int sub  = slot & 15;               // gt*2 + shalf
    const int b    = pr >> 3;
    const int h    = pr & 7;
    const int g0   = (sub >> 1) * 128;
    const int tb   = (sub & 1) * 32;          // tile base (S-half)
    const int blkid = pr * 16 + sub;          // scratch slot

    // Q B-frags: q = g0 + wave*32 + l31, dk = 16m + 8hi + j (Q pre-scaled 0.125)
    const bf16* qbase = Qb + (size_t)(b * G_LEN + g0 + wave * 32 + l31) * DM + h * DK + 8 * hi;
    const bf16x8 qf0 = *(const bf16x8*)(qbase);
    const bf16x8 qf1 = *(const bf16x8*)(qbase + 16);
    const bf16x8 qf2 = *(const bf16x8*)(qbase + 32);
    const bf16x8 qf3 = *(const bf16x8*)(qbase + 48);

    const bf16* Kh = Kb + (size_t)b * S_LEN * DM + h * DK;
    const bf16* Vh = Vt + (size_t)(b * NH + h) * DK * S_LEN;
    const u64*  mbv = mbits + b * (S_LEN / 64);
    const u64*  cbv = cbits + (size_t)(g0 + wave * 32 + l31) * (S_LEN / 64);

    // Staging: waves 0,1 stage K rows, waves 2,3 stage V rows (per-tile 8KB each).
    // lds off = wave*4096 + i*1024 + lane*16 -> row=(wave&1)*32+i*8+(lane>>3),
    // col16=lane&7. Source pre-swizzle col16s = (lane&7)^(row&7) (rule 21).
    const bool isK    = (wave < 2);
    const int rowbase = (wave & 1) * 32 + (lane >> 3);
    const int col16s  = (lane & 7) ^ (rowbase & 7);
    const int swz     = l31 & 7;   // read-side swizzle key

#define STAGE(tt, bufi) do {                                                   \
    char* ldw = sm + (bufi) * 16384 + wave * 4096;                             \
    _Pragma("unroll")                                                          \
    for (int i = 0; i < 4; ++i) {                                              \
        const int row = rowbase + i * 8;                                       \
        const bf16* g = isK                                                    \
            ? (Kh + (size_t)((tt) * 64 + row) * DM + col16s * 8)               \
            : (Vh + (size_t)row * S_LEN + (tt) * 64 + col16s * 8);             \
        stage16(g, ldw + i * 1024);                                            \
    }                                                                          \
} while (0)

    f32x16 accA = {};   // d = l31
    f32x16 accB = {};   // d = 32 + l31
    float lsum = 0.f;

    // prologue: tiles tb, tb+1 in flight (8 loads/thread outstanding)
    STAGE(tb + 0, 0);
    STAGE(tb + 1, 1);

    for (int t = 0; t < 32; ++t) {
        __builtin_amdgcn_s_barrier();              // A: buf[(t+2)%3] free
        __builtin_amdgcn_sched_barrier(0);
        if (t + 2 < 32) STAGE(tb + t + 2, (t + 2) % 3);
        if (t < 30)       asm volatile("s_waitcnt vmcnt(8)" ::: "memory");
        else if (t == 30) asm volatile("s_waitcnt vmcnt(4)" ::: "memory");
        else              asm volatile("s_waitcnt vmcnt(0)" ::: "memory");
        __builtin_amdgcn_s_barrier();              // B: buf[t%3] staged
        __builtin_amdgcn_sched_barrier(0);

        const char* bK = sm + (t % 3) * 16384;
        const char* bV = bK + 8192;

        // ---- QK^T (A = K from LDS, swizzled read): D[s_sub][q]
#define KF(ss, m) (*(const bf16x8*)(bK + ((ss) * 32 + l31) * 128 + (((2 * (m) + hi) ^ swz) * 16)))
        f32x16 c0 = {}, c1 = {};
        c0 = mfma32(KF(0, 0), qf0, c0); c0 = mfma32(KF(0, 1), qf1, c0);
        c0 = mfma32(KF(0, 2), qf2, c0); c0 = mfma32(KF(0, 3), qf3, c0);
        c1 = mfma32(KF(1, 0), qf0, c1); c1 = mfma32(KF(1, 1), qf1, c1);
        c1 = mfma32(KF(1, 2), qf2, c1); c1 = mfma32(KF(1, 3), qf3, c1);

        // ---- masks: one u64 per 64-s tile
        const u64 w64 = cbv[tb + t] & mbv[tb + t];
        const uint32_t kw0 = ((uint32_t)w64) >> (4 * hi);
        const uint32_t kw1 = ((uint32_t)(w64 >> 32)) >> (4 * hi);

        bf16x8 pa0, pa1, pb0, pb1;
        exppack(c0, kw0, lsum, pa0, pa1);
        exppack(c1, kw1, lsum, pb0, pb1);

        // ---- PV (B = V from LDS, swizzled read): acc[q][d]
#define VF(ss, ks, dh) (*(const bf16x8*)(bV + ((dh) * 32 + l31) * 128 + ((((ss) * 4 + (ks) * 2 + hi) ^ swz) * 16)))
        accA = mfma32(pa0, VF(0, 0, 0), accA); accA = mfma32(pa1, VF(0, 1, 0), accA);
        accA = mfma32(pb0, VF(1, 0, 0), accA); accA = mfma32(pb1, VF(1, 1, 0), accA);
        accB = mfma32(pa0, VF(0, 0, 1), accB); accB = mfma32(pa1, VF(0, 1, 1), accB);
        accB = mfma32(pb0, VF(1, 0, 1), accB); accB = mfma32(pb1, VF(1, 1, 1), accB);
    }
#undef KF
#undef VF
#undef STAGE

    // ---- write partials (no in-block merge needed) ----
    const float tl = lsum + __shfl_xor(lsum, 32);   // lane q=l31 holds half-denominator
    if (hi == 0) PL[blkid * 128 + wave * 32 + l31] = tl;
    bf16* po = PO + (size_t)blkid * 8192 + (wave * 32) * 64;
    #pragma unroll
    for (int reg = 0; reg < 16; ++reg) {
        const int q = (reg & 3) + 8 * (reg >> 2) + 4 * hi;
        po[q * 64 + l31]      = (bf16)accA[reg];
        po[q * 64 + 32 + l31] = (bf16)accB[reg];
    }
}

// ---------------------------------------------------------------------------
// Merge the two S-half partials -> AO. 2M elements, 4 per thread.
// ---------------------------------------------------------------------------
__global__ __launch_bounds__(256) void attn_merge(
    const bf16* __restrict__ PO, const float* __restrict__ PL, bf16* __restrict__ AO)
{
    const int idx = (blockIdx.x * 256 + threadIdx.x) * 4;   // 4 consecutive d
    const int row = idx >> 9;          // 0..4095 = b*1024 + g
    const int col = idx & 511;         // h*64 + d
    const int h   = col >> 6;
    const int d   = col & 63;
    const int pr  = (row >> 10) * 8 + h;
    const int gt  = (row & 1023) >> 7;
    const int q   = row & 127;
    const size_t base0 = ((size_t)(pr * 16 + gt * 2))     * 8192 + q * 64 + d;
    const size_t base1 = ((size_t)(pr * 16 + gt * 2 + 1)) * 8192 + q * 64 + d;
    const bf16x4 n0 = *(const bf16x4*)(PO + base0);
    const bf16x4 n1 = *(const bf16x4*)(PO + base1);
    const float pl = PL[(pr * 16 + gt * 2) * 128 + q] + PL[(pr * 16 + gt * 2 + 1) * 128 + q];
    const float inv = pl > 0.f ? 1.f / pl : 0.f;
    bf16x4 o;
    #pragma unroll
    for (int j = 0; j < 4; ++j) o[j] = (bf16)(((float)n0[j] + (float)n1[j]) * inv);
    *(bf16x4*)(AO + (size_t)row * 512 + col) = o;
}

// ---------------------------------------------------------------------------
// Row LayerNorm: one block per row (512 cols), 256 threads.
// ---------------------------------------------------------------------------
__global__ __launch_bounds__(256) void out_ln(
    const float* __restrict__ Y, const float* __restrict__ gam,
    const float* __restrict__ bet, float* __restrict__ out)
{
    const int row = blockIdx.x;
    const int tid = threadIdx.x;
    const float x0 = Y[(size_t)row * DM + tid];
    const float x1 = Y[(size_t)row * DM + 256 + tid];
    float s  = x0 + x1;
    float sq = x0 * x0 + x1 * x1;
    #pragma unroll
    for (int off = 1; off < 64; off <<= 1) {
        s  += __shfl_xor(s, off);
        sq += __shfl_xor(sq, off);
    }
    __shared__ float ss[4], ssq[4];
    const int wave = tid >> 6;
    if ((tid & 63) == 0) { ss[wave] = s; ssq[wave] = sq; }
    __syncthreads();
    s  = ss[0] + ss[1] + ss[2] + ss[3];
    sq = ssq[0] + ssq[1] + ssq[2] + ssq[3];
    const float mu  = s * (1.f / 512.f);
    const float var = sq * (1.f / 512.f) - mu * mu;
    const float rs  = rsqrtf(var + 1e-5f);
    out[(size_t)row * DM + tid]       = (x0 - mu) * rs * gam[tid] + bet[tid];
    out[(size_t)row * DM + 256 + tid] = (x1 - mu) * rs * gam[tid + 256] + bet[tid + 256];
}

// ---------------------------------------------------------------------------
extern "C" void kernel_launch(void* const* d_in, const int* in_sizes, int n_in,
                              void* d_out, int out_size, void* d_ws, size_t ws_size,
                              hipStream_t stream) {
    const float* queries     = (const float*)d_in[0];   // [4,1024,512]
    const float* keys_values = (const float*)d_in[1];   // [4,4096,512]
    const float* dq          = (const float*)d_in[2];   // [4,1,512]
    const float* dk          = (const float*)d_in[3];   // [4,1,512]
    const int*   mask        = (const int*)d_in[4];     // [4,4096]
    const void*  cis         = d_in[5];                 // [1024,4096] bool (dtype detected)
    const float* wq_w = (const float*)d_in[6];
    const float* wq_b = (const float*)d_in[7];
    const float* wk_w = (const float*)d_in[8];
    const float* wk_b = (const float*)d_in[9];
    const float* wv_w = (const float*)d_in[10];
    const float* wv_b = (const float*)d_in[11];
    const float* wo_w = (const float*)d_in[12];
    const float* wo_b = (const float*)d_in[13];
    const float* ln_g = (const float*)d_in[14];
    const float* ln_b = (const float*)d_in[15];
    float* out = (float*)d_out;

    char* ws = (char*)d_ws;
    bf16*  Qbf = (bf16*)(ws);                                   //  4 MB (pre-scaled x0.125)
    bf16*  Kbf = (bf16*)(ws + (4u << 20));                      // 16 MB [16384,512]
    bf16*  Vt  = (bf16*)(ws + (20u << 20));                     // 16 MB [4,8,64,4096]
    bf16*  AO  = (bf16*)(ws + (36u << 20));                     //  4 MB [4096,512]
    bf16*  PO  = (bf16*)(ws + (40u << 20));                     //  8 MB partial numerators
    float* Yw  = (float*)(ws + (40u << 20));                    //  8 MB (overlays PO; PO dead
                                                                //        before O-proj writes Yw)
    int*   cisflag = (int*)(ws + (48u << 20));                  //  4 B
    u64*   mbits   = (u64*)(ws + (48u << 20) + 4096);           //  2 KB [4][64]
    u64*   cbits   = (u64*)(ws + (48u << 20) + 8192);           // 512 KB [1024][64]
    float* PL      = (float*)(ws + (48u << 20) + 544 * 1024);   // 256 KB [512][128]

    detect_cis<<<1, 64, 0, stream>>>((const unsigned char*)cis, cisflag);
    pack_masks<<<(CIS_WORDS + BATCH * (S_LEN / 64) + 3) / 4, 256, 0, stream>>>(
        cis, mask, cisflag, cbits, mbits);

    // Q projection (pre-scaled by 1/sqrt(d_k)=0.125, exact pow2).
    gemm_proj<0, 0, 1024><<<dim3(64, 8), 256, 0, stream>>>(queries, wq_w, wq_b, dq, Qbf, 0.125f);
    // Fused K+V projections (shared A staging).
    gemm_kv<<<dim3(256, 8), 256, 0, stream>>>(keys_values, wk_w, wk_b, dk, wv_w, wv_b, Kbf, Vt);

    // Fused masked flash attention (LDS-shared K/V, 2-way S-split, partials)
    attn_kernel<<<512, 256, 0, stream>>>(Qbf, Kbf, Vt, mbits, cbits, PO, PL);
    attn_merge<<<2048, 256, 0, stream>>>(PO, PL, AO);

    // Output projection (bf16 A) -> f32 scratch (overwrites PO, now dead)
    gemm_proj<1, 1, 1024><<<dim3(64, 8), 256, 0, stream>>>(AO, wo_w, wo_b, nullptr, Yw, 1.0f);

    // LayerNorm -> d_out
    out_ln<<<4096, 256, 0, stream>>>(Yw, ln_g, ln_b, out);
}

// Round 13
// 216.786 us; speedup vs baseline: 2.1661x; 1.0554x over previous
//
#include <hip/hip_runtime.h>
#include <stdint.h>
#include <stddef.h>

typedef __bf16 bf16;
typedef __bf16 bf16x4 __attribute__((ext_vector_type(4)));
typedef __bf16 bf16x8 __attribute__((ext_vector_type(8)));
typedef float f32x4 __attribute__((ext_vector_type(4)));
typedef float f32x16 __attribute__((ext_vector_type(16)));
typedef unsigned long long u64;

#define BATCH 4
#define G_LEN 1024
#define S_LEN 4096
#define DM 512
#define NH 8
#define DK 64
#define CIS_WORDS (G_LEN * (S_LEN / 64))   // 65536

__device__ __forceinline__ f32x4 mfma16(bf16x8 a, bf16x8 b, f32x4 c) {
    return __builtin_amdgcn_mfma_f32_16x16x32_bf16(a, b, c, 0, 0, 0);
}
__device__ __forceinline__ f32x16 mfma32(bf16x8 a, bf16x8 b, f32x16 c) {
    return __builtin_amdgcn_mfma_f32_32x32x16_bf16(a, b, c, 0, 0, 0);
}
// v_cvt_pk_bf16_f32: dst.lo = bf16(lo), dst.hi = bf16(hi). No builtin (m240).
__device__ __forceinline__ uint32_t cvtpk(float lo, float hi_) {
    uint32_t r;
    asm("v_cvt_pk_bf16_f32 %0, %1, %2" : "=v"(r) : "v"(lo), "v"(hi_));
    return r;
}
// v_permlane32_swap_b32: a.lanes[32:64] <-> b.lanes[0:32] (gfx950).
__device__ __forceinline__ void pswap(uint32_t& a, uint32_t& b) {
    asm("v_permlane32_swap_b32 %0, %1" : "+v"(a), "+v"(b));
}
__device__ __forceinline__ bf16x8 mk8(uint32_t a, uint32_t b, uint32_t c, uint32_t d) {
    union { uint32_t u[4]; bf16x8 v; } x;
    x.u[0] = a; x.u[1] = b; x.u[2] = c; x.u[3] = d;
    return x.v;
}
// masked exp + bf16 pack + permlane redistribute into PV A-fragments.
__device__ __forceinline__ void exppack(f32x16& c, uint32_t kw, float& lsum,
                                        bf16x8& pa0, bf16x8& pa1) {
    #pragma unroll
    for (int reg = 0; reg < 16; ++reg) {
        const int bit = (reg & 3) + 8 * (reg >> 2);
        const float e = __expf(c[reg]);
        c[reg] = ((kw >> bit) & 1u) ? e : 0.f;
    }
    lsum += ((c[0] + c[1]) + (c[2] + c[3])) + ((c[4] + c[5]) + (c[6] + c[7]))
          + ((c[8] + c[9]) + (c[10] + c[11])) + ((c[12] + c[13]) + (c[14] + c[15]));
    uint32_t wa0 = cvtpk(c[0],  c[1]),  wa1 = cvtpk(c[2],  c[3]);
    uint32_t wb0 = cvtpk(c[4],  c[5]),  wb1 = cvtpk(c[6],  c[7]);
    uint32_t wc0 = cvtpk(c[8],  c[9]),  wc1 = cvtpk(c[10], c[11]);
    uint32_t wd0 = cvtpk(c[12], c[13]), wd1 = cvtpk(c[14], c[15]);
    pswap(wa0, wb0); pswap(wa1, wb1); pswap(wc0, wd0); pswap(wc1, wd1);
    pa0 = mk8(wa0, wa1, wb0, wb1);   // s = 8hi + 0..7
    pa1 = mk8(wc0, wc1, wd0, wd1);   // s = 16 + 8hi + 0..7
}
// async global->LDS, 16B/lane. LDS dest is WAVE-UNIFORM base (HW adds lane*16).
__device__ __forceinline__ void stage16(const bf16* g, char* l) {
    __builtin_amdgcn_global_load_lds(
        (const __attribute__((address_space(1))) void*)g,
        (__attribute__((address_space(3))) void*)l, 16, 0, 0);
}

// ---------------------------------------------------------------------------
// cis dtype detection (bool vs int32) — see round 1 notes. flag=1 -> bytes.
// ---------------------------------------------------------------------------
__global__ void detect_cis(const unsigned char* __restrict__ cis, int* __restrict__ flag) {
    int any = 0;
    for (int i = threadIdx.x; i < 16384; i += 64)
        any |= cis[4 * i + 1];
    #pragma unroll
    for (int off = 1; off < 64; off <<= 1) any |= __shfl_xor(any, off);
    if (threadIdx.x == 0) flag[0] = (any != 0) ? 1 : 0;
}

// ---------------------------------------------------------------------------
// Pack cis[g][s] and mask[b][s] into bit-words (one wave per u64 via ballot).
// ---------------------------------------------------------------------------
__global__ __launch_bounds__(256) void pack_masks(
    const void* __restrict__ cisv, const int* __restrict__ mask,
    const int* __restrict__ flag, u64* __restrict__ cbits, u64* __restrict__ mbits)
{
    const int wid  = blockIdx.x * 4 + (threadIdx.x >> 6);
    const int lane = threadIdx.x & 63;
    if (wid < CIS_WORDS) {
        int v;
        if (flag[0]) v = ((const unsigned char*)cisv)[(size_t)wid * 64 + lane];
        else         v = ((const int*)cisv)[(size_t)wid * 64 + lane];
        const u64 bits = __ballot(v != 0);
        if (lane == 0) cbits[wid] = bits;
    } else if (wid < CIS_WORDS + BATCH * (S_LEN / 64)) {
        const int w2 = wid - CIS_WORDS;               // b*64 + sw
        const u64 bits = __ballot(mask[w2 * 64 + lane] != 0);
        if (lane == 0) mbits[w2] = bits;
    }
}

// ---------------------------------------------------------------------------
// 128x128-tile GEMM: Y[m][n] = (sum_k X[m][k]*W[n][k] + bias[n] (+ shift)) * oscale
// 4 waves in 2x2; wave computes 64x64 (acc 16 x f32x4 = 64 VGPR).
// LDS A/B [128][72] bf16 (36KB, single-buffered, 2-way-free bank layout).
// Staging bytes per FLOP = half of the 64^2 tile (round-12 GEMM lever, m93).
// TRANS_OUT: V^T epilogue, bf16x4 stores (r = consecutive m).
// ---------------------------------------------------------------------------
template<int A_IS_BF16, int TRANS_OUT, int OUT_F32, int ROWS_PER_B>
__global__ __launch_bounds__(256) void gemm128(
    const void* __restrict__ Ap, const float* __restrict__ W,
    const float* __restrict__ bias, const float* __restrict__ shift,
    void* __restrict__ Out, float oscale)
{
    __shared__ bf16 As[128][72];
    __shared__ bf16 Bs[128][72];
    const int tid  = threadIdx.x;
    const int lane = tid & 63;
    const int wave = tid >> 6;
    const int l15  = lane & 15;
    const int l4   = lane >> 4;
    const int wr   = wave >> 1;        // wave row (0..1)
    const int wc   = wave & 1;         // wave col (0..1)
    const int m0   = blockIdx.x * 128;
    const int n0   = blockIdx.y * 128;

    f32x4 acc[4][4] = {};

    for (int kt = 0; kt < DM; kt += 64) {
        #pragma unroll
        for (int i = 0; i < 8; ++i) {
            const int q   = tid + i * 256;     // 0..2047
            const int row = q >> 4;            // 0..127
            const int kq  = (q & 15) * 4;      // 0..60
            bf16x4 av;
            if (A_IS_BF16) {
                av = *(const bf16x4*)((const bf16*)Ap + (size_t)(m0 + row) * DM + kt + kq);
            } else {
                const float4 v = *(const float4*)((const float*)Ap + (size_t)(m0 + row) * DM + kt + kq);
                av[0] = (bf16)v.x; av[1] = (bf16)v.y; av[2] = (bf16)v.z; av[3] = (bf16)v.w;
            }
            *(bf16x4*)&As[row][kq] = av;
            const float4 w = *(const float4*)(W + (size_t)(n0 + row) * DM + kt + kq);
            bf16x4 bv;
            bv[0] = (bf16)w.x; bv[1] = (bf16)w.y; bv[2] = (bf16)w.z; bv[3] = (bf16)w.w;
            *(bf16x4*)&Bs[row][kq] = bv;
        }
        __syncthreads();
        #pragma unroll
        for (int ks = 0; ks < 64; ks += 32) {
            bf16x8 af[4];
            #pragma unroll
            for (int mi = 0; mi < 4; ++mi)
                af[mi] = *(const bf16x8*)&As[wr * 64 + mi * 16 + l15][ks + 8 * l4];
            #pragma unroll
            for (int n = 0; n < 4; ++n) {
                const bf16x8 b = *(const bf16x8*)&Bs[wc * 64 + n * 16 + l15][ks + 8 * l4];
                #pragma unroll
                for (int mi = 0; mi < 4; ++mi)
                    acc[mi][n] = mfma16(af[mi], b, acc[mi][n]);
            }
        }
        __syncthreads();
    }

    #pragma unroll
    for (int n = 0; n < 4; ++n) {
        const int col = n0 + wc * 64 + n * 16 + l15;
        const float bv = bias[col];
        #pragma unroll
        for (int mi = 0; mi < 4; ++mi) {
            const int mb = m0 + wr * 64 + mi * 16 + l4 * 4;   // 4-aligned
            if (TRANS_OUT) {
                const int bb = mb / ROWS_PER_B;
                bf16x4 o;
                #pragma unroll
                for (int r = 0; r < 4; ++r) o[r] = (bf16)((acc[mi][n][r] + bv) * oscale);
                *(bf16x4*)((bf16*)Out + ((size_t)bb * DM + col) * ROWS_PER_B + (mb % ROWS_PER_B)) = o;
            } else {
                #pragma unroll
                for (int r = 0; r < 4; ++r) {
                    const int m = mb + r;
                    float v = acc[mi][n][r] + bv;
                    if (shift) v += shift[(m / ROWS_PER_B) * DM + col];
                    v *= oscale;
                    if (OUT_F32) ((float*)Out)[(size_t)m * DM + col] = v;
                    else         ((bf16*)Out)[(size_t)m * DM + col] = (bf16)v;
                }
            }
        }
    }
}

// ---------------------------------------------------------------------------
// Flash attention v3 (unchanged from round 12): LDS-shared K/V, 2-way S-split,
// 3-buf staging 2-ahead, counted vmcnt, reg-only P path, partials to scratch.
// ---------------------------------------------------------------------------
__global__ __launch_bounds__(256, 1) void attn_kernel(
    const bf16* __restrict__ Qb, const bf16* __restrict__ Kb,
    const bf16* __restrict__ Vt, const u64* __restrict__ mbits,
    const u64* __restrict__ cbits, bf16* __restrict__ PO, float* __restrict__ PL)
{
    __shared__ __align__(16) char sm[49152];   // 3 x (8KB K | 8KB V)

    const int tid  = threadIdx.x;
    const int lane = tid & 63;
    const int wave = tid >> 6;
    const int l31  = lane & 31;
    const int hi   = lane >> 5;

    // 512 blocks = 8 XCD x 4 pairs x (8 g-tiles x 2 S-halves).
    const int flat = blockIdx.x;
    const int xcd  = flat & 7;
    const int slot = flat >> 3;               // 0..63
    const int pr   = xcd * 4 + (slot >> 4);   // (b,h) pair 0..31
    const int sub  = slot & 15;               // gt*2 + shalf
    const int b    = pr >> 3;
    const int h    = pr & 7;
    const int g0   = (sub >> 1) * 128;
    const int tb   = (sub & 1) * 32;          // tile base (S-half)
    const int blkid = pr * 16 + sub;          // scratch slot

    // Q B-frags: q = g0 + wave*32 + l31, dk = 16m + 8hi + j (Q pre-scaled 0.125)
    const bf16* qbase = Qb + (size_t)(b * G_LEN + g0 + wave * 32 + l31) * DM + h * DK + 8 * hi;
    const bf16x8 qf0 = *(const bf16x8*)(qbase);
    const bf16x8 qf1 = *(const bf16x8*)(qbase + 16);
    const bf16x8 qf2 = *(const bf16x8*)(qbase + 32);
    const bf16x8 qf3 = *(const bf16x8*)(qbase + 48);

    const bf16* Kh = Kb + (size_t)b * S_LEN * DM + h * DK;
    const bf16* Vh = Vt + (size_t)(b * NH + h) * DK * S_LEN;
    const u64*  mbv = mbits + b * (S_LEN / 64);
    const u64*  cbv = cbits + (size_t)(g0 + wave * 32 + l31) * (S_LEN / 64);

    const bool isK    = (wave < 2);
    const int rowbase = (wave & 1) * 32 + (lane >> 3);
    const int col16s  = (lane & 7) ^ (rowbase & 7);
    const int swz     = l31 & 7;   // read-side swizzle key

#define STAGE(tt, bufi) do {                                                   \
    char* ldw = sm + (bufi) * 16384 + wave * 4096;                             \
    _Pragma("unroll")                                                          \
    for (int i = 0; i < 4; ++i) {                                              \
        const int row = rowbase + i * 8;                                       \
        const bf16* g = isK                                                    \
            ? (Kh + (size_t)((tt) * 64 + row) * DM + col16s * 8)               \
            : (Vh + (size_t)row * S_LEN + (tt) * 64 + col16s * 8);             \
        stage16(g, ldw + i * 1024);                                            \
    }                                                                          \
} while (0)

    f32x16 accA = {};   // d = l31
    f32x16 accB = {};   // d = 32 + l31
    float lsum = 0.f;

    STAGE(tb + 0, 0);
    STAGE(tb + 1, 1);

    for (int t = 0; t < 32; ++t) {
        __builtin_amdgcn_s_barrier();              // A: buf[(t+2)%3] free
        __builtin_amdgcn_sched_barrier(0);
        if (t + 2 < 32) STAGE(tb + t + 2, (t + 2) % 3);
        if (t < 30)       asm volatile("s_waitcnt vmcnt(8)" ::: "memory");
        else if (t == 30) asm volatile("s_waitcnt vmcnt(4)" ::: "memory");
        else              asm volatile("s_waitcnt vmcnt(0)" ::: "memory");
        __builtin_amdgcn_s_barrier();              // B: buf[t%3] staged
        __builtin_amdgcn_sched_barrier(0);

        const char* bK = sm + (t % 3) * 16384;
        const char* bV = bK + 8192;

#define KF(ss, m) (*(const bf16x8*)(bK + ((ss) * 32 + l31) * 128 + (((2 * (m) + hi) ^ swz) * 16)))
        f32x16 c0 = {}, c1 = {};
        c0 = mfma32(KF(0, 0), qf0, c0); c0 = mfma32(KF(0, 1), qf1, c0);
        c0 = mfma32(KF(0, 2), qf2, c0); c0 = mfma32(KF(0, 3), qf3, c0);
        c1 = mfma32(KF(1, 0), qf0, c1); c1 = mfma32(KF(1, 1), qf1, c1);
        c1 = mfma32(KF(1, 2), qf2, c1); c1 = mfma32(KF(1, 3), qf3, c1);

        const u64 w64 = cbv[tb + t] & mbv[tb + t];
        const uint32_t kw0 = ((uint32_t)w64) >> (4 * hi);
        const uint32_t kw1 = ((uint32_t)(w64 >> 32)) >> (4 * hi);

        bf16x8 pa0, pa1, pb0, pb1;
        exppack(c0, kw0, lsum, pa0, pa1);
        exppack(c1, kw1, lsum, pb0, pb1);

#define VF(ss, ks, dh) (*(const bf16x8*)(bV + ((dh) * 32 + l31) * 128 + ((((ss) * 4 + (ks) * 2 + hi) ^ swz) * 16)))
        accA = mfma32(pa0, VF(0, 0, 0), accA); accA = mfma32(pa1, VF(0, 1, 0), accA);
        accA = mfma32(pb0, VF(1, 0, 0), accA); accA = mfma32(pb1, VF(1, 1, 0), accA);
        accB = mfma32(pa0, VF(0, 0, 1), accB); accB = mfma32(pa1, VF(0, 1, 1), accB);
        accB = mfma32(pb0, VF(1, 0, 1), accB); accB = mfma32(pb1, VF(1, 1, 1), accB);
    }
#undef KF
#undef VF
#undef STAGE

    // ---- write partials ----
    const float tl = lsum + __shfl_xor(lsum, 32);
    if (hi == 0) PL[blkid * 128 + wave * 32 + l31] = tl;
    bf16* po = PO + (size_t)blkid * 8192 + (wave * 32) * 64;
    #pragma unroll
    for (int reg = 0; reg < 16; ++reg) {
        const int q = (reg & 3) + 8 * (reg >> 2) + 4 * hi;
        po[q * 64 + l31]      = (bf16)accA[reg];
        po[q * 64 + 32 + l31] = (bf16)accB[reg];
    }
}

// ---------------------------------------------------------------------------
// Merge the two S-half partials -> AO. 2M elements, 4 per thread.
// ---------------------------------------------------------------------------
__global__ __launch_bounds__(256) void attn_merge(
    const bf16* __restrict__ PO, const float* __restrict__ PL, bf16* __restrict__ AO)
{
    const int idx = (blockIdx.x * 256 + threadIdx.x) * 4;   // 4 consecutive d
    const int row = idx >> 9;          // 0..4095 = b*1024 + g
    const int col = idx & 511;         // h*64 + d
    const int h   = col >> 6;
    const int d   = col & 63;
    const int pr  = (row >> 10) * 8 + h;
    const int gt  = (row & 1023) >> 7;
    const int q   = row & 127;
    const size_t base0 = ((size_t)(pr * 16 + gt * 2))     * 8192 + q * 64 + d;
    const size_t base1 = ((size_t)(pr * 16 + gt * 2 + 1)) * 8192 + q * 64 + d;
    const bf16x4 n0 = *(const bf16x4*)(PO + base0);
    const bf16x4 n1 = *(const bf16x4*)(PO + base1);
    const float pl = PL[(pr * 16 + gt * 2) * 128 + q] + PL[(pr * 16 + gt * 2 + 1) * 128 + q];
    const float inv = pl > 0.f ? 1.f / pl : 0.f;
    bf16x4 o;
    #pragma unroll
    for (int j = 0; j < 4; ++j) o[j] = (bf16)(((float)n0[j] + (float)n1[j]) * inv);
    *(bf16x4*)(AO + (size_t)row * 512 + col) = o;
}

// ---------------------------------------------------------------------------
// Row LayerNorm: one block per row (512 cols), 256 threads.
// ---------------------------------------------------------------------------
__global__ __launch_bounds__(256) void out_ln(
    const float* __restrict__ Y, const float* __restrict__ gam,
    const float* __restrict__ bet, float* __restrict__ out)
{
    const int row = blockIdx.x;
    const int tid = threadIdx.x;
    const float x0 = Y[(size_t)row * DM + tid];
    const float x1 = Y[(size_t)row * DM + 256 + tid];
    float s  = x0 + x1;
    float sq = x0 * x0 + x1 * x1;
    #pragma unroll
    for (int off = 1; off < 64; off <<= 1) {
        s  += __shfl_xor(s, off);
        sq += __shfl_xor(sq, off);
    }
    __shared__ float ss[4], ssq[4];
    const int wave = tid >> 6;
    if ((tid & 63) == 0) { ss[wave] = s; ssq[wave] = sq; }
    __syncthreads();
    s  = ss[0] + ss[1] + ss[2] + ss[3];
    sq = ssq[0] + ssq[1] + ssq[2] + ssq[3];
    const float mu  = s * (1.f / 512.f);
    const float var = sq * (1.f / 512.f) - mu * mu;
    const float rs  = rsqrtf(var + 1e-5f);
    out[(size_t)row * DM + tid]       = (x0 - mu) * rs * gam[tid] + bet[tid];
    out[(size_t)row * DM + 256 + tid] = (x1 - mu) * rs * gam[tid + 256] + bet[tid + 256];
}

// ---------------------------------------------------------------------------
extern "C" void kernel_launch(void* const* d_in, const int* in_sizes, int n_in,
                              void* d_out, int out_size, void* d_ws, size_t ws_size,
                              hipStream_t stream) {
    const float* queries     = (const float*)d_in[0];   // [4,1024,512]
    const float* keys_values = (const float*)d_in[1];   // [4,4096,512]
    const float* dq          = (const float*)d_in[2];   // [4,1,512]
    const float* dk          = (const float*)d_in[3];   // [4,1,512]
    const int*   mask        = (const int*)d_in[4];     // [4,4096]
    const void*  cis         = d_in[5];                 // [1024,4096] bool (dtype detected)
    const float* wq_w = (const float*)d_in[6];
    const float* wq_b = (const float*)d_in[7];
    const float* wk_w = (const float*)d_in[8];
    const float* wk_b = (const float*)d_in[9];
    const float* wv_w = (const float*)d_in[10];
    const float* wv_b = (const float*)d_in[11];
    const float* wo_w = (const float*)d_in[12];
    const float* wo_b = (const float*)d_in[13];
    const float* ln_g = (const float*)d_in[14];
    const float* ln_b = (const float*)d_in[15];
    float* out = (float*)d_out;

    char* ws = (char*)d_ws;
    bf16*  Qbf = (bf16*)(ws);                                   //  4 MB (pre-scaled x0.125)
    bf16*  Kbf = (bf16*)(ws + (4u << 20));                      // 16 MB [16384,512]
    bf16*  Vt  = (bf16*)(ws + (20u << 20));                     // 16 MB [4,8,64,4096]
    bf16*  AO  = (bf16*)(ws + (36u << 20));                     //  4 MB [4096,512]
    bf16*  PO  = (bf16*)(ws + (40u << 20));                     //  8 MB partial numerators
    float* Yw  = (float*)(ws + (40u << 20));                    //  8 MB (overlays PO; PO dead
                                                                //        before O-proj writes Yw)
    int*   cisflag = (int*)(ws + (48u << 20));                  //  4 B
    u64*   mbits   = (u64*)(ws + (48u << 20) + 4096);           //  2 KB [4][64]
    u64*   cbits   = (u64*)(ws + (48u << 20) + 8192);           // 512 KB [1024][64]
    float* PL      = (float*)(ws + (48u << 20) + 544 * 1024);   // 256 KB [512][128]

    detect_cis<<<1, 64, 0, stream>>>((const unsigned char*)cis, cisflag);
    pack_masks<<<(CIS_WORDS + BATCH * (S_LEN / 64) + 3) / 4, 256, 0, stream>>>(
        cis, mask, cisflag, cbits, mbits);

    // Projections on the 128x128-tile GEMM.
    gemm128<0, 0, 0, 1024><<<dim3(32, 4),  256, 0, stream>>>(queries,     wq_w, wq_b, dq,      Qbf, 0.125f);
    gemm128<0, 0, 0, 4096><<<dim3(128, 4), 256, 0, stream>>>(keys_values, wk_w, wk_b, dk,      Kbf, 1.0f);
    gemm128<0, 1, 0, 4096><<<dim3(128, 4), 256, 0, stream>>>(keys_values, wv_w, wv_b, nullptr, Vt,  1.0f);

    // Fused masked flash attention (LDS-shared K/V, 2-way S-split, partials)
    attn_kernel<<<512, 256, 0, stream>>>(Qbf, Kbf, Vt, mbits, cbits, PO, PL);
    attn_merge<<<2048, 256, 0, stream>>>(PO, PL, AO);

    // Output projection (bf16 A) -> f32 scratch (overwrites PO, now dead)
    gemm128<1, 0, 1, 1024><<<dim3(32, 4),  256, 0, stream>>>(AO, wo_w, wo_b, nullptr, Yw, 1.0f);

    // LayerNorm -> d_out
    out_ln<<<4096, 256, 0, stream>>>(Yw, ln_g, ln_b, out);
}

// Round 14
// 214.220 us; speedup vs baseline: 2.1920x; 1.0120x over previous
//
#include <hip/hip_runtime.h>
#include <stdint.h>
#include <stddef.h>

typedef __bf16 bf16;
typedef __bf16 bf16x4 __attribute__((ext_vector_type(4)));
typedef __bf16 bf16x8 __attribute__((ext_vector_type(8)));
typedef float f32x4 __attribute__((ext_vector_type(4)));
typedef float f32x16 __attribute__((ext_vector_type(16)));
typedef unsigned long long u64;

#define BATCH 4
#define G_LEN 1024
#define S_LEN 4096
#define DM 512
#define NH 8
#define DK 64
#define CIS_WORDS (G_LEN * (S_LEN / 64))   // 65536

__device__ __forceinline__ f32x4 mfma16(bf16x8 a, bf16x8 b, f32x4 c) {
    return __builtin_amdgcn_mfma_f32_16x16x32_bf16(a, b, c, 0, 0, 0);
}
__device__ __forceinline__ f32x16 mfma32(bf16x8 a, bf16x8 b, f32x16 c) {
    return __builtin_amdgcn_mfma_f32_32x32x16_bf16(a, b, c, 0, 0, 0);
}
// v_cvt_pk_bf16_f32: dst.lo = bf16(lo), dst.hi = bf16(hi). No builtin (m240).
__device__ __forceinline__ uint32_t cvtpk(float lo, float hi_) {
    uint32_t r;
    asm("v_cvt_pk_bf16_f32 %0, %1, %2" : "=v"(r) : "v"(lo), "v"(hi_));
    return r;
}
// v_permlane32_swap_b32: a.lanes[32:64] <-> b.lanes[0:32] (gfx950).
__device__ __forceinline__ void pswap(uint32_t& a, uint32_t& b) {
    asm("v_permlane32_swap_b32 %0, %1" : "+v"(a), "+v"(b));
}
__device__ __forceinline__ bf16x8 mk8(uint32_t a, uint32_t b, uint32_t c, uint32_t d) {
    union { uint32_t u[4]; bf16x8 v; } x;
    x.u[0] = a; x.u[1] = b; x.u[2] = c; x.u[3] = d;
    return x.v;
}
// masked exp + bf16 pack + permlane redistribute into PV A-fragments.
__device__ __forceinline__ void exppack(f32x16& c, uint32_t kw, float& lsum,
                                        bf16x8& pa0, bf16x8& pa1) {
    #pragma unroll
    for (int reg = 0; reg < 16; ++reg) {
        const int bit = (reg & 3) + 8 * (reg >> 2);
        const float e = __expf(c[reg]);
        c[reg] = ((kw >> bit) & 1u) ? e : 0.f;
    }
    lsum += ((c[0] + c[1]) + (c[2] + c[3])) + ((c[4] + c[5]) + (c[6] + c[7]))
          + ((c[8] + c[9]) + (c[10] + c[11])) + ((c[12] + c[13]) + (c[14] + c[15]));
    uint32_t wa0 = cvtpk(c[0],  c[1]),  wa1 = cvtpk(c[2],  c[3]);
    uint32_t wb0 = cvtpk(c[4],  c[5]),  wb1 = cvtpk(c[6],  c[7]);
    uint32_t wc0 = cvtpk(c[8],  c[9]),  wc1 = cvtpk(c[10], c[11]);
    uint32_t wd0 = cvtpk(c[12], c[13]), wd1 = cvtpk(c[14], c[15]);
    pswap(wa0, wb0); pswap(wa1, wb1); pswap(wc0, wd0); pswap(wc1, wd1);
    pa0 = mk8(wa0, wa1, wb0, wb1);   // s = 8hi + 0..7
    pa1 = mk8(wc0, wc1, wd0, wd1);   // s = 16 + 8hi + 0..7
}
// async global->LDS, 16B/lane. LDS dest is WAVE-UNIFORM base (HW adds lane*16).
__device__ __forceinline__ void stage16(const bf16* g, char* l) {
    __builtin_amdgcn_global_load_lds(
        (const __attribute__((address_space(1))) void*)g,
        (__attribute__((address_space(3))) void*)l, 16, 0, 0);
}

// ---------------------------------------------------------------------------
// cis dtype detection (bool vs int32) — see round 1 notes. flag=1 -> bytes.
// ---------------------------------------------------------------------------
__global__ void detect_cis(const unsigned char* __restrict__ cis, int* __restrict__ flag) {
    int any = 0;
    for (int i = threadIdx.x; i < 16384; i += 64)
        any |= cis[4 * i + 1];
    #pragma unroll
    for (int off = 1; off < 64; off <<= 1) any |= __shfl_xor(any, off);
    if (threadIdx.x == 0) flag[0] = (any != 0) ? 1 : 0;
}

// ---------------------------------------------------------------------------
// Pack cis[g][s] and mask[b][s] into bit-words (one wave per u64 via ballot).
// ---------------------------------------------------------------------------
__global__ __launch_bounds__(256) void pack_masks(
    const void* __restrict__ cisv, const int* __restrict__ mask,
    const int* __restrict__ flag, u64* __restrict__ cbits, u64* __restrict__ mbits)
{
    const int wid  = blockIdx.x * 4 + (threadIdx.x >> 6);
    const int lane = threadIdx.x & 63;
    if (wid < CIS_WORDS) {
        int v;
        if (flag[0]) v = ((const unsigned char*)cisv)[(size_t)wid * 64 + lane];
        else         v = ((const int*)cisv)[(size_t)wid * 64 + lane];
        const u64 bits = __ballot(v != 0);
        if (lane == 0) cbits[wid] = bits;
    } else if (wid < CIS_WORDS + BATCH * (S_LEN / 64)) {
        const int w2 = wid - CIS_WORDS;               // b*64 + sw
        const u64 bits = __ballot(mask[w2 * 64 + lane] != 0);
        if (lane == 0) mbits[w2] = bits;
    }
}

// ---------------------------------------------------------------------------
// 128x128-tile GEMM (round-13, proven): 4 waves 2x2, wave 64x64 out.
// ---------------------------------------------------------------------------
template<int A_IS_BF16, int TRANS_OUT, int OUT_F32, int ROWS_PER_B>
__global__ __launch_bounds__(256) void gemm128(
    const void* __restrict__ Ap, const float* __restrict__ W,
    const float* __restrict__ bias, const float* __restrict__ shift,
    void* __restrict__ Out, float oscale)
{
    __shared__ bf16 As[128][72];
    __shared__ bf16 Bs[128][72];
    const int tid  = threadIdx.x;
    const int lane = tid & 63;
    const int wave = tid >> 6;
    const int l15  = lane & 15;
    const int l4   = lane >> 4;
    const int wr   = wave >> 1;
    const int wc   = wave & 1;
    const int m0   = blockIdx.x * 128;
    const int n0   = blockIdx.y * 128;

    f32x4 acc[4][4] = {};

    for (int kt = 0; kt < DM; kt += 64) {
        #pragma unroll
        for (int i = 0; i < 8; ++i) {
            const int q   = tid + i * 256;
            const int row = q >> 4;
            const int kq  = (q & 15) * 4;
            bf16x4 av;
            if (A_IS_BF16) {
                av = *(const bf16x4*)((const bf16*)Ap + (size_t)(m0 + row) * DM + kt + kq);
            } else {
                const float4 v = *(const float4*)((const float*)Ap + (size_t)(m0 + row) * DM + kt + kq);
                av[0] = (bf16)v.x; av[1] = (bf16)v.y; av[2] = (bf16)v.z; av[3] = (bf16)v.w;
            }
            *(bf16x4*)&As[row][kq] = av;
            const float4 w = *(const float4*)(W + (size_t)(n0 + row) * DM + kt + kq);
            bf16x4 bv;
            bv[0] = (bf16)w.x; bv[1] = (bf16)w.y; bv[2] = (bf16)w.z; bv[3] = (bf16)w.w;
            *(bf16x4*)&Bs[row][kq] = bv;
        }
        __syncthreads();
        #pragma unroll
        for (int ks = 0; ks < 64; ks += 32) {
            bf16x8 af[4];
            #pragma unroll
            for (int mi = 0; mi < 4; ++mi)
                af[mi] = *(const bf16x8*)&As[wr * 64 + mi * 16 + l15][ks + 8 * l4];
            #pragma unroll
            for (int n = 0; n < 4; ++n) {
                const bf16x8 b = *(const bf16x8*)&Bs[wc * 64 + n * 16 + l15][ks + 8 * l4];
                #pragma unroll
                for (int mi = 0; mi < 4; ++mi)
                    acc[mi][n] = mfma16(af[mi], b, acc[mi][n]);
            }
        }
        __syncthreads();
    }

    #pragma unroll
    for (int n = 0; n < 4; ++n) {
        const int col = n0 + wc * 64 + n * 16 + l15;
        const float bv = bias[col];
        #pragma unroll
        for (int mi = 0; mi < 4; ++mi) {
            const int mb = m0 + wr * 64 + mi * 16 + l4 * 4;
            if (TRANS_OUT) {
                const int bb = mb / ROWS_PER_B;
                bf16x4 o;
                #pragma unroll
                for (int r = 0; r < 4; ++r) o[r] = (bf16)((acc[mi][n][r] + bv) * oscale);
                *(bf16x4*)((bf16*)Out + ((size_t)bb * DM + col) * ROWS_PER_B + (mb % ROWS_PER_B)) = o;
            } else {
                #pragma unroll
                for (int r = 0; r < 4; ++r) {
                    const int m = mb + r;
                    float v = acc[mi][n][r] + bv;
                    if (shift) v += shift[(m / ROWS_PER_B) * DM + col];
                    v *= oscale;
                    if (OUT_F32) ((float*)Out)[(size_t)m * DM + col] = v;
                    else         ((bf16*)Out)[(size_t)m * DM + col] = (bf16)v;
                }
            }
        }
    }
}

// ---------------------------------------------------------------------------
// Flash attention v4: 4-way S-split for occupancy (round-13: 2 blocks/CU was
// the cap; Occ 19%, both pipes ~50% idle). Grid 1024 = 4 blocks/CU = 16
// waves/CU. LDS halved to 2 x 16KB double-buffer, 1-ahead staging, vmcnt(4)
// (waits current tile's 4 loads, keeps next tile's 4 in flight). Staged
// traffic unchanged (256MB total). Partials: 4 per (pair,gtile).
// ---------------------------------------------------------------------------
__global__ __launch_bounds__(256, 1) void attn_kernel(
    const bf16* __restrict__ Qb, const bf16* __restrict__ Kb,
    const bf16* __restrict__ Vt, const u64* __restrict__ mbits,
    const u64* __restrict__ cbits, bf16* __restrict__ PO, float* __restrict__ PL)
{
    __shared__ __align__(16) char sm[32768];   // 2 x (8KB K | 8KB V)

    const int tid  = threadIdx.x;
    const int lane = tid & 63;
    const int wave = tid >> 6;
    const int l31  = lane & 31;
    const int hi   = lane >> 5;

    // 1024 blocks = 8 XCD x 4 pairs x (8 g-tiles x 4 S-quarters).
    const int flat = blockIdx.x;
    const int xcd  = flat & 7;
    const int slot = flat >> 3;               // 0..127
    const int pr   = xcd * 4 + (slot >> 5);   // (b,h) pair 0..31
    const int sub  = slot & 31;               // gt*4 + squarter
    const int b    = pr >> 3;
    const int h    = pr & 7;
    const int g0   = (sub >> 2) * 128;
    const int tb   = (sub & 3) * 16;          // tile base (S-quarter, 16 tiles)
    const int blkid = pr * 32 + sub;          // scratch slot 0..1023

    // Q B-frags: q = g0 + wave*32 + l31, dk = 16m + 8hi + j (Q pre-scaled 0.125)
    const bf16* qbase = Qb + (size_t)(b * G_LEN + g0 + wave * 32 + l31) * DM + h * DK + 8 * hi;
    const bf16x8 qf0 = *(const bf16x8*)(qbase);
    const bf16x8 qf1 = *(const bf16x8*)(qbase + 16);
    const bf16x8 qf2 = *(const bf16x8*)(qbase + 32);
    const bf16x8 qf3 = *(const bf16x8*)(qbase + 48);

    const bf16* Kh = Kb + (size_t)b * S_LEN * DM + h * DK;
    const bf16* Vh = Vt + (size_t)(b * NH + h) * DK * S_LEN;
    const u64*  mbv = mbits + b * (S_LEN / 64);
    const u64*  cbv = cbits + (size_t)(g0 + wave * 32 + l31) * (S_LEN / 64);

    // Staging: waves 0,1 stage K rows, waves 2,3 stage V rows.
    // lds off = wave*4096 + i*1024 + lane*16 -> row=(wave&1)*32+i*8+(lane>>3),
    // col16=lane&7. Source pre-swizzle col16s = (lane&7)^(row&7) (rule 21).
    const bool isK    = (wave < 2);
    const int rowbase = (wave & 1) * 32 + (lane >> 3);
    const int col16s  = (lane & 7) ^ (rowbase & 7);
    const int swz     = l31 & 7;   // read-side swizzle key

#define STAGE(tt, bufi) do {                                                   \
    char* ldw = sm + (bufi) * 16384 + wave * 4096;                             \
    _Pragma("unroll")                                                          \
    for (int i = 0; i < 4; ++i) {                                              \
        const int row = rowbase + i * 8;                                       \
        const bf16* g = isK                                                    \
            ? (Kh + (size_t)((tt) * 64 + row) * DM + col16s * 8)               \
            : (Vh + (size_t)row * S_LEN + (tt) * 64 + col16s * 8);             \
        stage16(g, ldw + i * 1024);                                            \
    }                                                                          \
} while (0)

    f32x16 accA = {};   // d = l31
    f32x16 accB = {};   // d = 32 + l31
    float lsum = 0.f;

    // prologue: tile tb in flight
    STAGE(tb + 0, 0);

    for (int t = 0; t < 16; ++t) {
        __builtin_amdgcn_s_barrier();              // all waves done reading buf[(t+1)&1]
        __builtin_amdgcn_sched_barrier(0);
        if (t + 1 < 16) {
            STAGE(tb + t + 1, (t + 1) & 1);
            asm volatile("s_waitcnt vmcnt(4)" ::: "memory");   // tile t staged; t+1 in flight
        } else {
            asm volatile("s_waitcnt vmcnt(0)" ::: "memory");
        }
        __builtin_amdgcn_s_barrier();              // buf[t&1] staged for all waves
        __builtin_amdgcn_sched_barrier(0);

        const char* bK = sm + (t & 1) * 16384;
        const char* bV = bK + 8192;

        // ---- QK^T (A = K from LDS, swizzled read): D[s_sub][q]
#define KF(ss, m) (*(const bf16x8*)(bK + ((ss) * 32 + l31) * 128 + (((2 * (m) + hi) ^ swz) * 16)))
        f32x16 c0 = {}, c1 = {};
        c0 = mfma32(KF(0, 0), qf0, c0); c0 = mfma32(KF(0, 1), qf1, c0);
        c0 = mfma32(KF(0, 2), qf2, c0); c0 = mfma32(KF(0, 3), qf3, c0);
        c1 = mfma32(KF(1, 0), qf0, c1); c1 = mfma32(KF(1, 1), qf1, c1);
        c1 = mfma32(KF(1, 2), qf2, c1); c1 = mfma32(KF(1, 3), qf3, c1);

        // ---- masks: one u64 per 64-s tile
        const u64 w64 = cbv[tb + t] & mbv[tb + t];
        const uint32_t kw0 = ((uint32_t)w64) >> (4 * hi);
        const uint32_t kw1 = ((uint32_t)(w64 >> 32)) >> (4 * hi);

        bf16x8 pa0, pa1, pb0, pb1;
        exppack(c0, kw0, lsum, pa0, pa1);
        exppack(c1, kw1, lsum, pb0, pb1);

        // ---- PV (B = V from LDS, swizzled read): acc[q][d]
#define VF(ss, ks, dh) (*(const bf16x8*)(bV + ((dh) * 32 + l31) * 128 + ((((ss) * 4 + (ks) * 2 + hi) ^ swz) * 16)))
        accA = mfma32(pa0, VF(0, 0, 0), accA); accA = mfma32(pa1, VF(0, 1, 0), accA);
        accA = mfma32(pb0, VF(1, 0, 0), accA); accA = mfma32(pb1, VF(1, 1, 0), accA);
        accB = mfma32(pa0, VF(0, 0, 1), accB); accB = mfma32(pa1, VF(0, 1, 1), accB);
        accB = mfma32(pb0, VF(1, 0, 1), accB); accB = mfma32(pb1, VF(1, 1, 1), accB);
    }
#undef KF
#undef VF
#undef STAGE

    // ---- write partials ----
    const float tl = lsum + __shfl_xor(lsum, 32);
    if (hi == 0) PL[blkid * 128 + wave * 32 + l31] = tl;
    bf16* po = PO + (size_t)blkid * 8192 + (wave * 32) * 64;
    #pragma unroll
    for (int reg = 0; reg < 16; ++reg) {
        const int q = (reg & 3) + 8 * (reg >> 2) + 4 * hi;
        po[q * 64 + l31]      = (bf16)accA[reg];
        po[q * 64 + 32 + l31] = (bf16)accB[reg];
    }
}

// ---------------------------------------------------------------------------
// Merge the four S-quarter partials -> AO. 2M elements, 4 per thread.
// ---------------------------------------------------------------------------
__global__ __launch_bounds__(256) void attn_merge(
    const bf16* __restrict__ PO, const float* __restrict__ PL, bf16* __restrict__ AO)
{
    const int idx = (blockIdx.x * 256 + threadIdx.x) * 4;   // 4 consecutive d
    const int row = idx >> 9;          // 0..4095 = b*1024 + g
    const int col = idx & 511;         // h*64 + d
    const int h   = col >> 6;
    const int d   = col & 63;
    const int pr  = (row >> 10) * 8 + h;
    const int gt  = (row & 1023) >> 7;
    const int q   = row & 127;
    const int slot0 = pr * 32 + gt * 4;
    float num[4] = {0.f, 0.f, 0.f, 0.f};
    float pl = 0.f;
    #pragma unroll
    for (int s = 0; s < 4; ++s) {
        const bf16x4 n = *(const bf16x4*)(PO + (size_t)(slot0 + s) * 8192 + q * 64 + d);
        #pragma unroll
        for (int j = 0; j < 4; ++j) num[j] += (float)n[j];
        pl += PL[(slot0 + s) * 128 + q];
    }
    const float inv = pl > 0.f ? 1.f / pl : 0.f;
    bf16x4 o;
    #pragma unroll
    for (int j = 0; j < 4; ++j) o[j] = (bf16)(num[j] * inv);
    *(bf16x4*)(AO + (size_t)row * 512 + col) = o;
}

// ---------------------------------------------------------------------------
// Row LayerNorm: one block per row (512 cols), 256 threads.
// ---------------------------------------------------------------------------
__global__ __launch_bounds__(256) void out_ln(
    const float* __restrict__ Y, const float* __restrict__ gam,
    const float* __restrict__ bet, float* __restrict__ out)
{
    const int row = blockIdx.x;
    const int tid = threadIdx.x;
    const float x0 = Y[(size_t)row * DM + tid];
    const float x1 = Y[(size_t)row * DM + 256 + tid];
    float s  = x0 + x1;
    float sq = x0 * x0 + x1 * x1;
    #pragma unroll
    for (int off = 1; off < 64; off <<= 1) {
        s  += __shfl_xor(s, off);
        sq += __shfl_xor(sq, off);
    }
    __shared__ float ss[4], ssq[4];
    const int wave = tid >> 6;
    if ((tid & 63) == 0) { ss[wave] = s; ssq[wave] = sq; }
    __syncthreads();
    s  = ss[0] + ss[1] + ss[2] + ss[3];
    sq = ssq[0] + ssq[1] + ssq[2] + ssq[3];
    const float mu  = s * (1.f / 512.f);
    const float var = sq * (1.f / 512.f) - mu * mu;
    const float rs  = rsqrtf(var + 1e-5f);
    out[(size_t)row * DM + tid]       = (x0 - mu) * rs * gam[tid] + bet[tid];
    out[(size_t)row * DM + 256 + tid] = (x1 - mu) * rs * gam[tid + 256] + bet[tid + 256];
}

// ---------------------------------------------------------------------------
extern "C" void kernel_launch(void* const* d_in, const int* in_sizes, int n_in,
                              void* d_out, int out_size, void* d_ws, size_t ws_size,
                              hipStream_t stream) {
    const float* queries     = (const float*)d_in[0];   // [4,1024,512]
    const float* keys_values = (const float*)d_in[1];   // [4,4096,512]
    const float* dq          = (const float*)d_in[2];   // [4,1,512]
    const float* dk          = (const float*)d_in[3];   // [4,1,512]
    const int*   mask        = (const int*)d_in[4];     // [4,4096]
    const void*  cis         = d_in[5];                 // [1024,4096] bool (dtype detected)
    const float* wq_w = (const float*)d_in[6];
    const float* wq_b = (const float*)d_in[7];
    const float* wk_w = (const float*)d_in[8];
    const float* wk_b = (const float*)d_in[9];
    const float* wv_w = (const float*)d_in[10];
    const float* wv_b = (const float*)d_in[11];
    const float* wo_w = (const float*)d_in[12];
    const float* wo_b = (const float*)d_in[13];
    const float* ln_g = (const float*)d_in[14];
    const float* ln_b = (const float*)d_in[15];
    float* out = (float*)d_out;

    char* ws = (char*)d_ws;
    bf16*  Qbf = (bf16*)(ws);                                   //  4 MB (pre-scaled x0.125)
    bf16*  Kbf = (bf16*)(ws + (4u << 20));                      // 16 MB [16384,512]
    bf16*  Vt  = (bf16*)(ws + (20u << 20));                     // 16 MB [4,8,64,4096]
    bf16*  AO  = (bf16*)(ws + (36u << 20));                     //  4 MB [4096,512]
    bf16*  PO  = (bf16*)(ws + (40u << 20));                     // 16 MB partial numerators [1024][8192]
    float* Yw  = (float*)(ws + (40u << 20));                    //  8 MB (overlays PO; PO dead
                                                                //        before O-proj writes Yw)
    int*   cisflag = (int*)(ws + (56u << 20));                  //  4 B
    u64*   mbits   = (u64*)(ws + (56u << 20) + 4096);           //  2 KB [4][64]
    u64*   cbits   = (u64*)(ws + (56u << 20) + 8192);           // 512 KB [1024][64]
    float* PL      = (float*)(ws + (56u << 20) + 544 * 1024);   // 512 KB [1024][128]

    detect_cis<<<1, 64, 0, stream>>>((const unsigned char*)cis, cisflag);
    pack_masks<<<(CIS_WORDS + BATCH * (S_LEN / 64) + 3) / 4, 256, 0, stream>>>(
        cis, mask, cisflag, cbits, mbits);

    // Projections on the 128x128-tile GEMM.
    gemm128<0, 0, 0, 1024><<<dim3(32, 4),  256, 0, stream>>>(queries,     wq_w, wq_b, dq,      Qbf, 0.125f);
    gemm128<0, 0, 0, 4096><<<dim3(128, 4), 256, 0, stream>>>(keys_values, wk_w, wk_b, dk,      Kbf, 1.0f);
    gemm128<0, 1, 0, 4096><<<dim3(128, 4), 256, 0, stream>>>(keys_values, wv_w, wv_b, nullptr, Vt,  1.0f);

    // Fused masked flash attention (4-way S-split, dbuf staging, partials)
    attn_kernel<<<1024, 256, 0, stream>>>(Qbf, Kbf, Vt, mbits, cbits, PO, PL);
    attn_merge<<<2048, 256, 0, stream>>>(PO, PL, AO);

    // Output projection (bf16 A) -> f32 scratch (overwrites PO, now dead)
    gemm128<1, 0, 1, 1024><<<dim3(32, 4),  256, 0, stream>>>(AO, wo_w, wo_b, nullptr, Yw, 1.0f);

    // LayerNorm -> d_out
    out_ln<<<4096, 256, 0, stream>>>(Yw, ln_g, ln_b, out);
}